// Round 12
// baseline (331.062 us; speedup 1.0000x reference)
//
#include <hip/hip_runtime.h>

typedef __bf16 bf16;
typedef __bf16 bf16x4 __attribute__((ext_vector_type(4)));
typedef __bf16 bf16x8 __attribute__((ext_vector_type(8)));
typedef float  f32x4  __attribute__((ext_vector_type(4)));
typedef float  f32x16 __attribute__((ext_vector_type(16)));

#define GLDS16(gsrc, ldst)                                                    \
  __builtin_amdgcn_global_load_lds(                                          \
      (const __attribute__((address_space(1))) void*)(gsrc),                 \
      (__attribute__((address_space(3))) void*)(ldst), 16, 0, 0)

#define MFMA16(a, b, c) __builtin_amdgcn_mfma_f32_16x16x32_bf16((a), (b), (c), 0, 0, 0)
#define MFMA32(a, b, c) __builtin_amdgcn_mfma_f32_32x32x16_bf16((a), (b), (c), 0, 0, 0)
#define PLSWAP(a, b) asm volatile("v_permlane32_swap_b32 %0, %1" : "+v"(a), "+v"(b))
// raw barrier with compiler-level memory fences (no vmcnt(0) drain)
#define BARRAW()                                                              \
  do {                                                                        \
    asm volatile("" ::: "memory");                                            \
    __builtin_amdgcn_s_barrier();                                             \
    asm volatile("" ::: "memory");                                            \
  } while (0)

__device__ inline unsigned pk2(float a, float b) {
  union { bf16 h[2]; unsigned u; } t;
  t.h[0] = (bf16)a; t.h[1] = (bf16)b;
  return t.u;
}

// ---------------- fused f32 -> bf16 convert for all 5 inputs ----------------
__global__ __launch_bounds__(256) void cvt5_kernel(const float* __restrict__ x,
                                                   const float* __restrict__ wq,
                                                   const float* __restrict__ wk,
                                                   const float* __restrict__ wv,
                                                   const float* __restrict__ wo,
                                                   bf16* __restrict__ xb,
                                                   bf16* __restrict__ wqkv,
                                                   bf16* __restrict__ wob) {
  int i = blockIdx.x * 256 + threadIdx.x;
  const float* src; bf16* dst; int off;
  if (i < 2097152)      { src = x;  dst = xb;             off = i; }
  else if (i < 3145728) { src = wq; dst = wqkv;           off = i - 2097152; }
  else if (i < 3407872) { src = wk; dst = wqkv + 4194304; off = i - 3145728; }
  else if (i < 3670016) { src = wv; dst = wqkv + 5242880; off = i - 3407872; }
  else                  { src = wo; dst = wob;            off = i - 3670016; }
  f32x4 f = *(const f32x4*)(src + (size_t)off * 4);
  bf16x4 o4;
#pragma unroll
  for (int j = 0; j < 4; ++j) o4[j] = (bf16)f[j];
  *(bf16x4*)(dst + (size_t)off * 4) = o4;
}

// ---------------- V -> swizzled V^T global ([b][g][64][L]) ----------------
__global__ __launch_bounds__(256) void vtr_kernel(const bf16* __restrict__ v,
                                                  bf16* __restrict__ vt) {
  constexpr int L = 2048, QS = 3072;
  const int kv0 = blockIdx.x * 64;
  const int bg = blockIdx.y;            // b*8+g
  const int tid = threadIdx.x;
  __shared__ bf16 t[64 * 64];

#pragma unroll
  for (int i = 0; i < 2; ++i) {
    int c = tid + 256 * i;
    int kv = c >> 3, e = c & 7;
    bf16x8 row = *(const bf16x8*)(v + (size_t)((bg >> 3) * L + kv0 + kv) * QS +
                                  (bg & 7) * 64 + e * 8);
#pragma unroll
    for (int j = 0; j < 8; ++j)
      t[(8 * e + j) * 64 + (kv ^ (8 * (e ^ j)))] = row[j];
  }
  __syncthreads();

  const int d = tid >> 2, c4 = tid & 3;
  bf16* orow = vt + ((size_t)bg * 64 + d) * L + kv0;
#pragma unroll
  for (int dl = 0; dl < 2; ++dl) {
    int sc = 2 * c4 + dl;
    bf16x8 ch = *(const bf16x8*)&t[d * 64 + 8 * (sc ^ (d >> 3))];
    *(bf16x8*)(orow + 8 * sc) = ch;
  }
}

// ---------------- 256x256 8-phase GEMM: C = A * B^T (T1+T2+T3+T4+T5) -------
// BM=BN=256, BK=64, 512 thr = 8 waves (2M x 4N), per-wave C 128x64.
// LDS 128KB: a_lds/b_lds[2 dbuf][2 half][128x64], st_16x32 swizzle
// (k ^= ((row>>2)&1)<<4) applied via inverse-swizzled GLOBAL source (rule #21).
// Schedule: tile u phases p0..p3 = C-quadrant (p>>1, p&1) x K=64 (16 MFMA);
// one half of tile u+1 staged per phase (targets slot freed end of tile u-1,
// >=1 barrier margin — WAR ledger in journal). Counted vmcnt(2) at p0 only.
// ROPE epilogue: wave's 64-col span = one head; partner d+32 = acc[mt][nt^2].
template <typename OutT, bool ROPE>
__global__ __launch_bounds__(512, 2) void gemm256(const bf16* __restrict__ A,
                                                  const bf16* __restrict__ Bm,
                                                  OutT* __restrict__ C,
                                                  int M, int N, int K,
                                                  const float* __restrict__ cosb,
                                                  const float* __restrict__ sinb) {
  __shared__ bf16 a_lds[2][2][128 * 64];
  __shared__ bf16 b_lds[2][2][128 * 64];
  const int tid = threadIdx.x;
  const int wv = tid >> 6, lane = tid & 63;
  const int lr = lane & 15, lg = lane >> 4;
  const int wm = wv >> 2, wn = wv & 3;          // 2M x 4N wave grid
  const int nbn = N >> 8;
  const int nwg = (M >> 8) * nbn;
  const int sid = ((int)blockIdx.x & 7) * (nwg >> 3) + ((int)blockIdx.x >> 3);
  const int m0 = (sid / nbn) << 8, n0 = (sid % nbn) << 8;
  const int NT = K >> 6;

  f32x4 acc[8][4];
#pragma unroll
  for (int i = 0; i < 8; ++i)
#pragma unroll
    for (int j = 0; j < 4; ++j) acc[i][j] = f32x4{0.f, 0.f, 0.f, 0.f};

  // stage one half-tile (128 rows x 64 k = 16KB): 2 gload_lds per thread.
  // source chunk pre-swizzled (cs = c ^ ((row>>2)&1)<<1) so LDS dest is linear.
  auto stA = [&](int u, int h) {
#pragma unroll
    for (int i = 0; i < 2; ++i) {
      int ci = tid + 512 * i;
      int row = ci >> 3, c = ci & 7;
      int cs = c ^ (((row >> 2) & 1) << 1);
      GLDS16(A + (size_t)(m0 + h * 128 + row) * K + u * 64 + cs * 8,
             &a_lds[u & 1][h][(wv * 64 + 512 * i) * 8]);
    }
  };
  auto stB = [&](int u, int h) {
#pragma unroll
    for (int i = 0; i < 2; ++i) {
      int ci = tid + 512 * i;
      int row = ci >> 3, c = ci & 7;
      int cs = c ^ (((row >> 2) & 1) << 1);
      GLDS16(Bm + (size_t)(n0 + h * 128 + row) * K + u * 64 + cs * 8,
             &b_lds[u & 1][h][(wv * 64 + 512 * i) * 8]);
    }
  };

  // prologue: tile 0 fully staged
  stA(0, 0); stA(0, 1); stB(0, 0); stB(0, 1);
  asm volatile("s_waitcnt vmcnt(0)" ::: "memory");
  BARRAW();

#pragma unroll 2
  for (int u = 0; u < NT; ++u) {
    const int s = u & 1;
    const bool pf = (u + 1 < NT);
#pragma unroll
    for (int p = 0; p < 4; ++p) {
      if (pf) {                       // stage half p of tile u+1
        if (p == 0)      stA(u + 1, 0);
        else if (p == 1) stA(u + 1, 1);
        else if (p == 2) stB(u + 1, 0);
        else             stB(u + 1, 1);
      }
      if (p == 0) {                   // tile boundary: counted drain + publish
        if (pf) asm volatile("s_waitcnt vmcnt(2)" ::: "memory");
        else    asm volatile("s_waitcnt vmcnt(0)" ::: "memory");
        BARRAW();
      }
      const int mh = p >> 1, nh = p & 1;
      bf16x8 af[4][2], bfr[2][2];
#pragma unroll
      for (int mtq = 0; mtq < 4; ++mtq) {
        int row = mh * 64 + mtq * 16 + lr;      // wave's A half = wm
        int sw = ((row >> 2) & 1) << 4;
#pragma unroll
        for (int kc = 0; kc < 2; ++kc)
          af[mtq][kc] = *(const bf16x8*)&a_lds[s][wm][row * 64 + ((kc * 32 + lg * 8) ^ sw)];
      }
#pragma unroll
      for (int ntq = 0; ntq < 2; ++ntq) {
        int row = (wn & 1) * 64 + nh * 32 + ntq * 16 + lr;  // B half = wn>>1
        int sw = ((row >> 2) & 1) << 4;
#pragma unroll
        for (int kc = 0; kc < 2; ++kc)
          bfr[ntq][kc] = *(const bf16x8*)&b_lds[s][wn >> 1][row * 64 + ((kc * 32 + lg * 8) ^ sw)];
      }
      __builtin_amdgcn_s_setprio(1);
#pragma unroll
      for (int mtq = 0; mtq < 4; ++mtq)
#pragma unroll
        for (int ntq = 0; ntq < 2; ++ntq)
#pragma unroll
          for (int kc = 0; kc < 2; ++kc)
            acc[mh * 4 + mtq][nh * 2 + ntq] =
                MFMA16(af[mtq][kc], bfr[ntq][kc], acc[mh * 4 + mtq][nh * 2 + ntq]);
      __builtin_amdgcn_s_setprio(0);
      BARRAW();                       // publish this phase's reads-complete
    }
  }

  // ---- epilogue (+ fused RoPE for QKV) ----
  const int hb = (n0 + wn * 64) >> 6;           // head block (wave-uniform)
  const bool dorope = ROPE && (hb < 40);
  const float rsc = (ROPE && hb < 32) ? 0.18033688011112042f : 1.0f;
#pragma unroll
  for (int mt = 0; mt < 8; ++mt)
#pragma unroll
    for (int r = 0; r < 4; ++r) {
      int mm = m0 + wm * 128 + mt * 16 + 4 * lg + r;   // C/D row = 4*lg+reg
      float ov[4];
      if (dorope) {
        int l = mm & 2047;
        const float* cp = cosb + l * 64 + lr;
        const float* sp = sinb + l * 64 + lr;
        float a0 = acc[mt][0][r], a1 = acc[mt][1][r];
        float a2 = acc[mt][2][r], a3 = acc[mt][3][r];
        ov[0] = (a0 * cp[0]  - a2 * sp[0])  * rsc;     // d = lr
        ov[1] = (a1 * cp[16] - a3 * sp[16]) * rsc;     // d = 16+lr
        ov[2] = (a2 * cp[32] + a0 * sp[32]) * rsc;     // d = 32+lr
        ov[3] = (a3 * cp[48] + a1 * sp[48]) * rsc;     // d = 48+lr
      } else {
#pragma unroll
        for (int nt = 0; nt < 4; ++nt) ov[nt] = acc[mt][nt][r];
      }
#pragma unroll
      for (int nt = 0; nt < 4; ++nt) {
        int nn = n0 + wn * 64 + nt * 16 + lr;          // C/D col = lr
        C[(size_t)mm * N + nn] = (OutT)ov[nt];
      }
    }
}

// ---------------- causal GQA flash attention (swapped QK^T, 32x32) ----------
// Split-KV for u>=7 q-tiles (two half-range blocks + combine); longest-first.
__global__ __launch_bounds__(256, 4) void attn_kernel(const bf16* __restrict__ q,
                                                      const bf16* __restrict__ k,
                                                      const bf16* __restrict__ vtg,
                                                      bf16* __restrict__ o,
                                                      bf16* __restrict__ opart,
                                                      float* __restrict__ mpart,
                                                      float* __restrict__ lpart,
                                                      int split_n, int umax) {
  constexpr int L = 2048;
  constexpr int QS = 3072;
  constexpr int OS = 2048;
  const int id = blockIdx.x;
  int bh, u, ts, te, pidx;
  bool split;
  if (id < split_n) {
    bh = id & 63;
    int t = id >> 6;
    u = 15 - (t >> 1);
    int s = t & 1;
    ts = s * (u + 1);
    te = ts + (u + 1);
    pidx = (bh * 9 + (u - 7)) * 2 + s;
    split = true;
  } else {
    int e = id - split_n;
    bh = e & 63;
    u = umax - (e >> 6);
    ts = 0;
    te = 2 * u + 2;
    pidx = 0;
    split = false;
  }
  const int q0 = u * 128;
  const int b = bh >> 5, h = bh & 31, g = h >> 2;
  const int tid = threadIdx.x;
  const int w = tid >> 6, lane = tid & 63;
  const int lc = lane & 31;
  const int H  = lane >> 5;
  const int off4 = 4 * H;
  const int qw = q0 + w * 32;
  const int qg = qw + lc;

  __shared__ bf16 k_lds[2][64 * 64];
  __shared__ bf16 vt_lds[2][64 * 64];

  bf16x8 qf[4];
  {
    const bf16* qrow = q + (size_t)(b * L + qg) * QS + h * 64 + 8 * H;
#pragma unroll
    for (int s = 0; s < 4; ++s) qf[s] = *(const bf16x8*)(qrow + 16 * s);
  }

  f32x16 acc0, acc1;
#pragma unroll
  for (int r = 0; r < 16; ++r) { acc0[r] = 0.f; acc1[r] = 0.f; }
  float m_run = -1e30f, l_run = 0.f;

  const bf16* vbase = vtg + (size_t)(b * 8 + g) * 64 * L;

  auto stageK = [&](int kv0, int buf) {
#pragma unroll
    for (int i = 0; i < 2; ++i) {
      int c = tid + 256 * i;
      int kvr = c >> 3, c8 = c & 7;
      GLDS16(k + (size_t)(b * L + kv0 + kvr) * QS + g * 64 + ((c8 ^ (kvr & 7)) * 8),
             &k_lds[buf][(w * 64 + 256 * i) * 8]);
    }
  };
  auto stageV = [&](int kv0, int buf) {
#pragma unroll
    for (int i = 0; i < 2; ++i) {
      int c = tid + 256 * i;
      GLDS16(vbase + (size_t)(c >> 3) * L + kv0 + (c & 7) * 8,
             &vt_lds[buf][(w * 64 + 256 * i) * 8]);
    }
  };

  stageK(ts * 64, 0);
  stageV(ts * 64, 0);
  __syncthreads();

  for (int it = ts; it < te; ++it) {
    const int cur = (it - ts) & 1;
    const int kv0 = it * 64;
    const bool notlast = (it + 1 < te);
    if (notlast) {
      stageK(kv0 + 64, cur ^ 1);
      stageV(kv0 + 64, cur ^ 1);
    }

    if (kv0 <= qw + 31) {
      f32x16 p0, p1;
#pragma unroll
      for (int r = 0; r < 16; ++r) { p0[r] = 0.f; p1[r] = 0.f; }
      __builtin_amdgcn_s_setprio(1);
#pragma unroll
      for (int s = 0; s < 4; ++s) {
        int ch = ((2 * s + H) ^ (lc & 7)) * 8;
        bf16x8 kf0 = *(const bf16x8*)&k_lds[cur][lc * 64 + ch];
        bf16x8 kf1 = *(const bf16x8*)&k_lds[cur][(32 + lc) * 64 + ch];
        p0 = MFMA32(kf0, qf[s], p0);
        p1 = MFMA32(kf1, qf[s], p1);
      }
      __builtin_amdgcn_s_setprio(0);

      if (kv0 + 63 > qw) {
#pragma unroll
        for (int r = 0; r < 16; ++r) {
          int kvl = kv0 + (r & 3) + 8 * (r >> 2) + off4;
          if (kvl > qg)      p0[r] = -1e30f;
          if (kvl + 32 > qg) p1[r] = -1e30f;
        }
      }

      float mt = -1e30f;
#pragma unroll
      for (int r = 0; r < 16; ++r) mt = fmaxf(mt, fmaxf(p0[r], p1[r]));
      mt = fmaxf(mt, __shfl_xor(mt, 32));
      const int defer = __all(mt <= m_run + 11.0f);
      float alpha = 1.f;
      if (!defer) {
        float mn = fmaxf(m_run, mt);
        alpha = exp2f(m_run - mn);
        m_run = mn;
      }
      float ls = 0.f;
#pragma unroll
      for (int r = 0; r < 16; ++r) {
        p0[r] = exp2f(p0[r] - m_run);
        p1[r] = exp2f(p1[r] - m_run);
        ls += p0[r] + p1[r];
      }
      ls += __shfl_xor(ls, 32);
      l_run = l_run * alpha + ls;
      if (!defer) {
#pragma unroll
        for (int r = 0; r < 16; ++r) {
          float aq = __shfl(alpha, ((r & 3) + 8 * (r >> 2)) + off4);
          acc0[r] *= aq;
          acc1[r] *= aq;
        }
      }

      unsigned A[16];
#pragma unroll
      for (int i = 0; i < 8; ++i) {
        A[i]     = pk2(p0[2 * i], p0[2 * i + 1]);
        A[8 + i] = pk2(p1[2 * i], p1[2 * i + 1]);
      }
#pragma unroll
      for (int base = 0; base < 16; base += 4) {
        PLSWAP(A[base],     A[base + 2]);
        PLSWAP(A[base + 1], A[base + 3]);
      }

      __builtin_amdgcn_s_setprio(1);
#pragma unroll
      for (int sp = 0; sp < 4; ++sp) {
        union { unsigned u[4]; bf16x8 v8; } pa;
#pragma unroll
        for (int jx = 0; jx < 4; ++jx) pa.u[jx] = A[4 * sp + jx];
        int ch = ((2 * sp + H) ^ (lc & 7)) * 8;
        bf16x8 vf0 = *(const bf16x8*)&vt_lds[cur][lc * 64 + ch];
        bf16x8 vf1 = *(const bf16x8*)&vt_lds[cur][(32 + lc) * 64 + ch];
        acc0 = MFMA32(pa.v8, vf0, acc0);
        acc1 = MFMA32(pa.v8, vf1, acc1);
      }
      __builtin_amdgcn_s_setprio(0);
    }

    __syncthreads();
  }

  if (split) {
    bf16* op = opart + (size_t)pidx * (128 * 64);
#pragma unroll
    for (int r = 0; r < 16; ++r) {
      int qrow = w * 32 + (r & 3) + 8 * (r >> 2) + off4;
      op[qrow * 64 + lc]      = (bf16)acc0[r];
      op[qrow * 64 + 32 + lc] = (bf16)acc1[r];
    }
    if (H == 0) {
      mpart[(size_t)pidx * 128 + w * 32 + lc] = m_run;
      lpart[(size_t)pidx * 128 + w * 32 + lc] = l_run;
    }
  } else {
#pragma unroll
    for (int r = 0; r < 16; ++r) {
      int qrow = (r & 3) + 8 * (r >> 2) + off4;
      float lq = __shfl(l_run, qrow);
      float inv = 1.f / lq;
      size_t orow = (size_t)(b * L + qw + qrow) * OS + h * 64;
      o[orow + lc]      = (bf16)(acc0[r] * inv);
      o[orow + 32 + lc] = (bf16)(acc1[r] * inv);
    }
  }
}

// ---------------- combine split-KV partials ----------------
__global__ __launch_bounds__(256) void comb_kernel(const bf16* __restrict__ opart,
                                                   const float* __restrict__ mpart,
                                                   const float* __restrict__ lpart,
                                                   bf16* __restrict__ o) {
  constexpr int L = 2048, OS = 2048;
  const int blk = blockIdx.x;
  const int bh = blk / 9, uu = blk % 9, u = uu + 7;
  const int b = bh >> 5, h = bh & 31;
  const int q0 = u * 128;
  const int t = threadIdx.x;
  const int row = t >> 1, dh = (t & 1) * 32;

  const size_t s0 = (size_t)blk * 2, s1 = s0 + 1;
  float m0 = mpart[s0 * 128 + row], m1 = mpart[s1 * 128 + row];
  float l0 = lpart[s0 * 128 + row], l1 = lpart[s1 * 128 + row];
  float m = fmaxf(m0, m1);
  float w0 = exp2f(m0 - m), w1 = exp2f(m1 - m);
  float inv = 1.f / (l0 * w0 + l1 * w1);

  const bf16* O0 = opart + s0 * (128 * 64) + row * 64 + dh;
  const bf16* O1 = opart + s1 * (128 * 64) + row * 64 + dh;
  bf16* orow = o + (size_t)(b * L + q0 + row) * OS + h * 64 + dh;
#pragma unroll
  for (int j = 0; j < 4; ++j) {
    bf16x8 a = *(const bf16x8*)(O0 + 8 * j);
    bf16x8 c = *(const bf16x8*)(O1 + 8 * j);
    bf16x8 r;
#pragma unroll
    for (int e = 0; e < 8; ++e)
      r[e] = (bf16)(((float)a[e] * w0 + (float)c[e] * w1) * inv);
    *(bf16x8*)(orow + 8 * j) = r;
  }
}

extern "C" void kernel_launch(void* const* d_in, const int* in_sizes, int n_in,
                              void* d_out, int out_size, void* d_ws, size_t ws_size,
                              hipStream_t stream) {
  (void)in_sizes; (void)n_in; (void)out_size;
  const float* x    = (const float*)d_in[0];
  const float* cosb = (const float*)d_in[1];
  const float* sinb = (const float*)d_in[2];
  const float* Wq   = (const float*)d_in[3];
  const float* Wk   = (const float*)d_in[4];
  const float* Wv   = (const float*)d_in[5];
  const float* Wo   = (const float*)d_in[6];

  constexpr int B = 2, L = 2048, D = 2048, H = 32, G = 8;
  constexpr int M = B * L;           // 4096
  constexpr int DKV = G * 64;        // 512
  constexpr int NQKV = D + 2 * DKV;  // 3072

  char* p = (char*)d_ws;
  bf16*  xb   = (bf16*)p;  p += (size_t)M * D * 2;
  bf16*  wqkv = (bf16*)p;  p += (size_t)NQKV * D * 2;
  bf16*  wob  = (bf16*)p;  p += (size_t)D * D * 2;
  bf16*  qkv  = (bf16*)p;  p += (size_t)M * NQKV * 2;
  bf16*  vtg  = (bf16*)p;  p += (size_t)B * G * 64 * L * 2;
  bf16*  opart = (bf16*)p; p += (size_t)1152 * 128 * 64 * 2;
  float* mpart = (float*)p; p += (size_t)1152 * 128 * 4;
  float* lpart = (float*)p; p += (size_t)1152 * 128 * 4;
  bf16*  ob   = xb;  // xb dead after QKV GEMM

  const bool do_split = ws_size >= (size_t)(p - (char*)d_ws);

  cvt5_kernel<<<dim3(18432), 256, 0, stream>>>(x, Wq, Wk, Wv, Wo, xb, wqkv, wob);

  // fused QKV projection + RoPE epilogue (8-phase 256^2; 192 blocks)
  gemm256<bf16, true><<<dim3((M / 256) * (NQKV / 256)), 512, 0, stream>>>(
      xb, wqkv, qkv, M, NQKV, D, cosb, sinb);

  // V -> swizzled V^T global (consumed by attention via global_load_lds)
  vtr_kernel<<<dim3(L / 64, B * G), 256, 0, stream>>>(qkv + D + DKV, vtg);

  if (do_split) {
    attn_kernel<<<dim3(1600), 256, 0, stream>>>(qkv, qkv + D, vtg, ob,
                                                opart, mpart, lpart, 1152, 6);
    comb_kernel<<<dim3(576), 256, 0, stream>>>(opart, mpart, lpart, ob);
  } else {
    attn_kernel<<<dim3(1024), 256, 0, stream>>>(qkv, qkv + D, vtg, ob,
                                                opart, mpart, lpart, 0, 15);
  }

  // output projection (8-phase 256^2; 128 blocks)
  gemm256<float, false><<<dim3((M / 256) * (D / 256)), 512, 0, stream>>>(
      ob, wob, (float*)d_out, M, D, D, nullptr, nullptr);
}

// Round 13
// 254.326 us; speedup vs baseline: 1.3017x; 1.3017x over previous
//
#include <hip/hip_runtime.h>

typedef __bf16 bf16;
typedef __bf16 bf16x4 __attribute__((ext_vector_type(4)));
typedef __bf16 bf16x8 __attribute__((ext_vector_type(8)));
typedef float  f32x4  __attribute__((ext_vector_type(4)));
typedef float  f32x16 __attribute__((ext_vector_type(16)));

#define GLDS16(gsrc, ldst)                                                    \
  __builtin_amdgcn_global_load_lds(                                          \
      (const __attribute__((address_space(1))) void*)(gsrc),                 \
      (__attribute__((address_space(3))) void*)(ldst), 16, 0, 0)

#define MFMA16(a, b, c) __builtin_amdgcn_mfma_f32_16x16x32_bf16((a), (b), (c), 0, 0, 0)
#define MFMA32(a, b, c) __builtin_amdgcn_mfma_f32_32x32x16_bf16((a), (b), (c), 0, 0, 0)
#define PLSWAP(a, b) asm volatile("v_permlane32_swap_b32 %0, %1" : "+v"(a), "+v"(b))
// raw barrier with compiler-level memory fences (no vmcnt(0) drain)
#define BARRAW()                                                              \
  do {                                                                        \
    asm volatile("" ::: "memory");                                            \
    __builtin_amdgcn_s_barrier();                                             \
    asm volatile("" ::: "memory");                                            \
  } while (0)

__device__ inline unsigned pk2(float a, float b) {
  union { bf16 h[2]; unsigned u; } t;
  t.h[0] = (bf16)a; t.h[1] = (bf16)b;
  return t.u;
}

// ---------------- fused f32 -> bf16 convert for all 5 inputs ----------------
__global__ __launch_bounds__(256) void cvt5_kernel(const float* __restrict__ x,
                                                   const float* __restrict__ wq,
                                                   const float* __restrict__ wk,
                                                   const float* __restrict__ wv,
                                                   const float* __restrict__ wo,
                                                   bf16* __restrict__ xb,
                                                   bf16* __restrict__ wqkv,
                                                   bf16* __restrict__ wob) {
  int i = blockIdx.x * 256 + threadIdx.x;
  const float* src; bf16* dst; int off;
  if (i < 2097152)      { src = x;  dst = xb;             off = i; }
  else if (i < 3145728) { src = wq; dst = wqkv;           off = i - 2097152; }
  else if (i < 3407872) { src = wk; dst = wqkv + 4194304; off = i - 3145728; }
  else if (i < 3670016) { src = wv; dst = wqkv + 5242880; off = i - 3407872; }
  else                  { src = wo; dst = wob;            off = i - 3670016; }
  f32x4 f = *(const f32x4*)(src + (size_t)off * 4);
  bf16x4 o4;
#pragma unroll
  for (int j = 0; j < 4; ++j) o4[j] = (bf16)f[j];
  *(bf16x4*)(dst + (size_t)off * 4) = o4;
}

// ---------------- V -> swizzled V^T global ([b][g][64][L]) ----------------
__global__ __launch_bounds__(256) void vtr_kernel(const bf16* __restrict__ v,
                                                  bf16* __restrict__ vt) {
  constexpr int L = 2048, QS = 3072;
  const int kv0 = blockIdx.x * 64;
  const int bg = blockIdx.y;            // b*8+g
  const int tid = threadIdx.x;
  __shared__ bf16 t[64 * 64];

#pragma unroll
  for (int i = 0; i < 2; ++i) {
    int c = tid + 256 * i;
    int kv = c >> 3, e = c & 7;
    bf16x8 row = *(const bf16x8*)(v + (size_t)((bg >> 3) * L + kv0 + kv) * QS +
                                  (bg & 7) * 64 + e * 8);
#pragma unroll
    for (int j = 0; j < 8; ++j)
      t[(8 * e + j) * 64 + (kv ^ (8 * (e ^ j)))] = row[j];
  }
  __syncthreads();

  const int d = tid >> 2, c4 = tid & 3;
  bf16* orow = vt + ((size_t)bg * 64 + d) * L + kv0;
#pragma unroll
  for (int dl = 0; dl < 2; ++dl) {
    int sc = 2 * c4 + dl;
    bf16x8 ch = *(const bf16x8*)&t[d * 64 + 8 * (sc ^ (d >> 3))];
    *(bf16x8*)(orow + 8 * sc) = ch;
  }
}

// ---------------- 256x256 8-phase GEMM: C = A * B^T (T1..T5, fixed) --------
// BM=BN=256, BK=64, 512 thr = 8 waves (2M x 4N), per-wave C 128x64.
// R12 fixes: (1) 2 barriers/tile (RAW publish at p0, WAR guard at tile end) —
// phases drift, LDS || MFMA overlaps across waves. (2) gray-code quadrants
// (0,0),(0,1),(1,1),(1,0): A-half reused 2 phases, B-sub adjacent phases ->
// 28 ds_read_b128/tile (was 48). (3) swizzle = element-bit-5 ^ (row>>2)&1:
// per-b128 8 rows hit words 0-15, 8 hit 16-31 -> exact 8-access/bank floor.
// Staging: A halves of tile u+1 at p0, B halves at p1; vmcnt(4) at p0 forces
// tile u's 8 loads complete, leaves the 4 A-loads flying (3-phase lead).
template <typename OutT, bool ROPE>
__global__ __launch_bounds__(512, 2) void gemm256(const bf16* __restrict__ A,
                                                  const bf16* __restrict__ Bm,
                                                  OutT* __restrict__ C,
                                                  int M, int N, int K,
                                                  const float* __restrict__ cosb,
                                                  const float* __restrict__ sinb) {
  __shared__ bf16 a_lds[2][2][128 * 64];
  __shared__ bf16 b_lds[2][2][128 * 64];
  const int tid = threadIdx.x;
  const int wv = tid >> 6, lane = tid & 63;
  const int lr = lane & 15, lg = lane >> 4;
  const int wm = wv >> 2, wn = wv & 3;          // 2M x 4N wave grid
  const int nbn = N >> 8;
  const int nwg = (M >> 8) * nbn;
  const int sid = ((int)blockIdx.x & 7) * (nwg >> 3) + ((int)blockIdx.x >> 3);
  const int m0 = (sid / nbn) << 8, n0 = (sid % nbn) << 8;
  const int NT = K >> 6;

  f32x4 acc[8][4];
#pragma unroll
  for (int i = 0; i < 8; ++i)
#pragma unroll
    for (int j = 0; j < 4; ++j) acc[i][j] = f32x4{0.f, 0.f, 0.f, 0.f};

  // stage one half-tile (128 rows x 64 k = 16KB): 2 gload_lds per thread.
  // source chunk pre-swizzled (cs = c ^ ((row>>2)&1)<<2) -> linear LDS dest.
  auto stA = [&](int u, int h) {
#pragma unroll
    for (int i = 0; i < 2; ++i) {
      int ci = tid + 512 * i;
      int row = ci >> 3, c = ci & 7;
      int cs = c ^ (((row >> 2) & 1) << 2);
      GLDS16(A + (size_t)(m0 + h * 128 + row) * K + u * 64 + cs * 8,
             &a_lds[u & 1][h][(wv * 64 + 512 * i) * 8]);
    }
  };
  auto stB = [&](int u, int h) {
#pragma unroll
    for (int i = 0; i < 2; ++i) {
      int ci = tid + 512 * i;
      int row = ci >> 3, c = ci & 7;
      int cs = c ^ (((row >> 2) & 1) << 2);
      GLDS16(Bm + (size_t)(n0 + h * 128 + row) * K + u * 64 + cs * 8,
             &b_lds[u & 1][h][(wv * 64 + 512 * i) * 8]);
    }
  };
  // fragment loads (element-bit-5 swizzle on read)
  auto ldA = [&](bf16x8 af[4][2], int s, int mh) {
#pragma unroll
    for (int mtq = 0; mtq < 4; ++mtq) {
      int row = mh * 64 + mtq * 16 + lr;
      int sw = ((row >> 2) & 1) << 5;
#pragma unroll
      for (int kc = 0; kc < 2; ++kc)
        af[mtq][kc] = *(const bf16x8*)&a_lds[s][wm][row * 64 + ((kc * 32 + lg * 8) ^ sw)];
    }
  };
  auto ldB = [&](bf16x8 bfr[2][2], int s, int nh) {
#pragma unroll
    for (int ntq = 0; ntq < 2; ++ntq) {
      int row = (wn & 1) * 64 + nh * 32 + ntq * 16 + lr;
      int sw = ((row >> 2) & 1) << 5;
#pragma unroll
      for (int kc = 0; kc < 2; ++kc)
        bfr[ntq][kc] = *(const bf16x8*)&b_lds[s][wn >> 1][row * 64 + ((kc * 32 + lg * 8) ^ sw)];
    }
  };
  auto quad = [&](bf16x8 af[4][2], bf16x8 bfr[2][2], int mh, int nh) {
    __builtin_amdgcn_s_setprio(1);
#pragma unroll
    for (int mtq = 0; mtq < 4; ++mtq)
#pragma unroll
      for (int ntq = 0; ntq < 2; ++ntq)
#pragma unroll
        for (int kc = 0; kc < 2; ++kc)
          acc[mh * 4 + mtq][nh * 2 + ntq] =
              MFMA16(af[mtq][kc], bfr[ntq][kc], acc[mh * 4 + mtq][nh * 2 + ntq]);
    __builtin_amdgcn_s_setprio(0);
  };

  // prologue: tile 0 fully staged
  stA(0, 0); stA(0, 1); stB(0, 0); stB(0, 1);
  asm volatile("s_waitcnt vmcnt(0)" ::: "memory");
  BARRAW();

  for (int u = 0; u < NT; ++u) {
    const int s = u & 1;
    const bool pf = (u + 1 < NT);
    bf16x8 af[4][2], bfr[2][2];
    // ---- p0: stage A(u+1); counted drain; publish; quadrant (0,0) ----
    if (pf) { stA(u + 1, 0); stA(u + 1, 1); }
    if (pf) asm volatile("s_waitcnt vmcnt(4)" ::: "memory");
    else    asm volatile("s_waitcnt vmcnt(0)" ::: "memory");
    BARRAW();
    ldA(af, s, 0); ldB(bfr, s, 0);
    quad(af, bfr, 0, 0);
    // ---- p1: stage B(u+1); quadrant (0,1) — A reused ----
    if (pf) { stB(u + 1, 0); stB(u + 1, 1); }
    ldB(bfr, s, 1);
    quad(af, bfr, 0, 1);
    // ---- p2: quadrant (1,1) — B reused ----
    ldA(af, s, 1);
    quad(af, bfr, 1, 1);
    // ---- p3: quadrant (1,0) ----
    ldB(bfr, s, 0);
    quad(af, bfr, 1, 0);
    BARRAW();   // WAR guard: all waves done reading buf s before next stages
  }

  // ---- epilogue (+ fused RoPE for QKV) ----
  const int hb = (n0 + wn * 64) >> 6;           // head block (wave-uniform)
  const bool dorope = ROPE && (hb < 40);
  const float rsc = (ROPE && hb < 32) ? 0.18033688011112042f : 1.0f;
#pragma unroll
  for (int mt = 0; mt < 8; ++mt)
#pragma unroll
    for (int r = 0; r < 4; ++r) {
      int mm = m0 + wm * 128 + mt * 16 + 4 * lg + r;   // C/D row = 4*lg+reg
      float ov[4];
      if (dorope) {
        int l = mm & 2047;
        const float* cp = cosb + l * 64 + lr;
        const float* sp = sinb + l * 64 + lr;
        float a0 = acc[mt][0][r], a1 = acc[mt][1][r];
        float a2 = acc[mt][2][r], a3 = acc[mt][3][r];
        ov[0] = (a0 * cp[0]  - a2 * sp[0])  * rsc;     // d = lr
        ov[1] = (a1 * cp[16] - a3 * sp[16]) * rsc;     // d = 16+lr
        ov[2] = (a2 * cp[32] + a0 * sp[32]) * rsc;     // d = 32+lr
        ov[3] = (a3 * cp[48] + a1 * sp[48]) * rsc;     // d = 48+lr
      } else {
#pragma unroll
        for (int nt = 0; nt < 4; ++nt) ov[nt] = acc[mt][nt][r];
      }
#pragma unroll
      for (int nt = 0; nt < 4; ++nt) {
        int nn = n0 + wn * 64 + nt * 16 + lr;          // C/D col = lr
        C[(size_t)mm * N + nn] = (OutT)ov[nt];
      }
    }
}

// ---------------- causal GQA flash attention (swapped QK^T, 32x32) ----------
// Split-KV for u>=7 q-tiles (two half-range blocks + combine); longest-first.
__global__ __launch_bounds__(256, 4) void attn_kernel(const bf16* __restrict__ q,
                                                      const bf16* __restrict__ k,
                                                      const bf16* __restrict__ vtg,
                                                      bf16* __restrict__ o,
                                                      bf16* __restrict__ opart,
                                                      float* __restrict__ mpart,
                                                      float* __restrict__ lpart,
                                                      int split_n, int umax) {
  constexpr int L = 2048;
  constexpr int QS = 3072;
  constexpr int OS = 2048;
  const int id = blockIdx.x;
  int bh, u, ts, te, pidx;
  bool split;
  if (id < split_n) {
    bh = id & 63;
    int t = id >> 6;
    u = 15 - (t >> 1);
    int s = t & 1;
    ts = s * (u + 1);
    te = ts + (u + 1);
    pidx = (bh * 9 + (u - 7)) * 2 + s;
    split = true;
  } else {
    int e = id - split_n;
    bh = e & 63;
    u = umax - (e >> 6);
    ts = 0;
    te = 2 * u + 2;
    pidx = 0;
    split = false;
  }
  const int q0 = u * 128;
  const int b = bh >> 5, h = bh & 31, g = h >> 2;
  const int tid = threadIdx.x;
  const int w = tid >> 6, lane = tid & 63;
  const int lc = lane & 31;
  const int H  = lane >> 5;
  const int off4 = 4 * H;
  const int qw = q0 + w * 32;
  const int qg = qw + lc;

  __shared__ bf16 k_lds[2][64 * 64];
  __shared__ bf16 vt_lds[2][64 * 64];

  bf16x8 qf[4];
  {
    const bf16* qrow = q + (size_t)(b * L + qg) * QS + h * 64 + 8 * H;
#pragma unroll
    for (int s = 0; s < 4; ++s) qf[s] = *(const bf16x8*)(qrow + 16 * s);
  }

  f32x16 acc0, acc1;
#pragma unroll
  for (int r = 0; r < 16; ++r) { acc0[r] = 0.f; acc1[r] = 0.f; }
  float m_run = -1e30f, l_run = 0.f;

  const bf16* vbase = vtg + (size_t)(b * 8 + g) * 64 * L;

  auto stageK = [&](int kv0, int buf) {
#pragma unroll
    for (int i = 0; i < 2; ++i) {
      int c = tid + 256 * i;
      int kvr = c >> 3, c8 = c & 7;
      GLDS16(k + (size_t)(b * L + kv0 + kvr) * QS + g * 64 + ((c8 ^ (kvr & 7)) * 8),
             &k_lds[buf][(w * 64 + 256 * i) * 8]);
    }
  };
  auto stageV = [&](int kv0, int buf) {
#pragma unroll
    for (int i = 0; i < 2; ++i) {
      int c = tid + 256 * i;
      GLDS16(vbase + (size_t)(c >> 3) * L + kv0 + (c & 7) * 8,
             &vt_lds[buf][(w * 64 + 256 * i) * 8]);
    }
  };

  stageK(ts * 64, 0);
  stageV(ts * 64, 0);
  __syncthreads();

  for (int it = ts; it < te; ++it) {
    const int cur = (it - ts) & 1;
    const int kv0 = it * 64;
    const bool notlast = (it + 1 < te);
    if (notlast) {
      stageK(kv0 + 64, cur ^ 1);
      stageV(kv0 + 64, cur ^ 1);
    }

    if (kv0 <= qw + 31) {
      f32x16 p0, p1;
#pragma unroll
      for (int r = 0; r < 16; ++r) { p0[r] = 0.f; p1[r] = 0.f; }
      __builtin_amdgcn_s_setprio(1);
#pragma unroll
      for (int s = 0; s < 4; ++s) {
        int ch = ((2 * s + H) ^ (lc & 7)) * 8;
        bf16x8 kf0 = *(const bf16x8*)&k_lds[cur][lc * 64 + ch];
        bf16x8 kf1 = *(const bf16x8*)&k_lds[cur][(32 + lc) * 64 + ch];
        p0 = MFMA32(kf0, qf[s], p0);
        p1 = MFMA32(kf1, qf[s], p1);
      }
      __builtin_amdgcn_s_setprio(0);

      if (kv0 + 63 > qw) {
#pragma unroll
        for (int r = 0; r < 16; ++r) {
          int kvl = kv0 + (r & 3) + 8 * (r >> 2) + off4;
          if (kvl > qg)      p0[r] = -1e30f;
          if (kvl + 32 > qg) p1[r] = -1e30f;
        }
      }

      float mt = -1e30f;
#pragma unroll
      for (int r = 0; r < 16; ++r) mt = fmaxf(mt, fmaxf(p0[r], p1[r]));
      mt = fmaxf(mt, __shfl_xor(mt, 32));
      const int defer = __all(mt <= m_run + 11.0f);
      float alpha = 1.f;
      if (!defer) {
        float mn = fmaxf(m_run, mt);
        alpha = exp2f(m_run - mn);
        m_run = mn;
      }
      float ls = 0.f;
#pragma unroll
      for (int r = 0; r < 16; ++r) {
        p0[r] = exp2f(p0[r] - m_run);
        p1[r] = exp2f(p1[r] - m_run);
        ls += p0[r] + p1[r];
      }
      ls += __shfl_xor(ls, 32);
      l_run = l_run * alpha + ls;
      if (!defer) {
#pragma unroll
        for (int r = 0; r < 16; ++r) {
          float aq = __shfl(alpha, ((r & 3) + 8 * (r >> 2)) + off4);
          acc0[r] *= aq;
          acc1[r] *= aq;
        }
      }

      unsigned A[16];
#pragma unroll
      for (int i = 0; i < 8; ++i) {
        A[i]     = pk2(p0[2 * i], p0[2 * i + 1]);
        A[8 + i] = pk2(p1[2 * i], p1[2 * i + 1]);
      }
#pragma unroll
      for (int base = 0; base < 16; base += 4) {
        PLSWAP(A[base],     A[base + 2]);
        PLSWAP(A[base + 1], A[base + 3]);
      }

      __builtin_amdgcn_s_setprio(1);
#pragma unroll
      for (int sp = 0; sp < 4; ++sp) {
        union { unsigned u[4]; bf16x8 v8; } pa;
#pragma unroll
        for (int jx = 0; jx < 4; ++jx) pa.u[jx] = A[4 * sp + jx];
        int ch = ((2 * sp + H) ^ (lc & 7)) * 8;
        bf16x8 vf0 = *(const bf16x8*)&vt_lds[cur][lc * 64 + ch];
        bf16x8 vf1 = *(const bf16x8*)&vt_lds[cur][(32 + lc) * 64 + ch];
        acc0 = MFMA32(pa.v8, vf0, acc0);
        acc1 = MFMA32(pa.v8, vf1, acc1);
      }
      __builtin_amdgcn_s_setprio(0);
    }

    __syncthreads();
  }

  if (split) {
    bf16* op = opart + (size_t)pidx * (128 * 64);
#pragma unroll
    for (int r = 0; r < 16; ++r) {
      int qrow = w * 32 + (r & 3) + 8 * (r >> 2) + off4;
      op[qrow * 64 + lc]      = (bf16)acc0[r];
      op[qrow * 64 + 32 + lc] = (bf16)acc1[r];
    }
    if (H == 0) {
      mpart[(size_t)pidx * 128 + w * 32 + lc] = m_run;
      lpart[(size_t)pidx * 128 + w * 32 + lc] = l_run;
    }
  } else {
#pragma unroll
    for (int r = 0; r < 16; ++r) {
      int qrow = (r & 3) + 8 * (r >> 2) + off4;
      float lq = __shfl(l_run, qrow);
      float inv = 1.f / lq;
      size_t orow = (size_t)(b * L + qw + qrow) * OS + h * 64;
      o[orow + lc]      = (bf16)(acc0[r] * inv);
      o[orow + 32 + lc] = (bf16)(acc1[r] * inv);
    }
  }
}

// ---------------- combine split-KV partials ----------------
__global__ __launch_bounds__(256) void comb_kernel(const bf16* __restrict__ opart,
                                                   const float* __restrict__ mpart,
                                                   const float* __restrict__ lpart,
                                                   bf16* __restrict__ o) {
  constexpr int L = 2048, OS = 2048;
  const int blk = blockIdx.x;
  const int bh = blk / 9, uu = blk % 9, u = uu + 7;
  const int b = bh >> 5, h = bh & 31;
  const int q0 = u * 128;
  const int t = threadIdx.x;
  const int row = t >> 1, dh = (t & 1) * 32;

  const size_t s0 = (size_t)blk * 2, s1 = s0 + 1;
  float m0 = mpart[s0 * 128 + row], m1 = mpart[s1 * 128 + row];
  float l0 = lpart[s0 * 128 + row], l1 = lpart[s1 * 128 + row];
  float m = fmaxf(m0, m1);
  float w0 = exp2f(m0 - m), w1 = exp2f(m1 - m);
  float inv = 1.f / (l0 * w0 + l1 * w1);

  const bf16* O0 = opart + s0 * (128 * 64) + row * 64 + dh;
  const bf16* O1 = opart + s1 * (128 * 64) + row * 64 + dh;
  bf16* orow = o + (size_t)(b * L + q0 + row) * OS + h * 64 + dh;
#pragma unroll
  for (int j = 0; j < 4; ++j) {
    bf16x8 a = *(const bf16x8*)(O0 + 8 * j);
    bf16x8 c = *(const bf16x8*)(O1 + 8 * j);
    bf16x8 r;
#pragma unroll
    for (int e = 0; e < 8; ++e)
      r[e] = (bf16)(((float)a[e] * w0 + (float)c[e] * w1) * inv);
    *(bf16x8*)(orow + 8 * j) = r;
  }
}

extern "C" void kernel_launch(void* const* d_in, const int* in_sizes, int n_in,
                              void* d_out, int out_size, void* d_ws, size_t ws_size,
                              hipStream_t stream) {
  (void)in_sizes; (void)n_in; (void)out_size;
  const float* x    = (const float*)d_in[0];
  const float* cosb = (const float*)d_in[1];
  const float* sinb = (const float*)d_in[2];
  const float* Wq   = (const float*)d_in[3];
  const float* Wk   = (const float*)d_in[4];
  const float* Wv   = (const float*)d_in[5];
  const float* Wo   = (const float*)d_in[6];

  constexpr int B = 2, L = 2048, D = 2048, H = 32, G = 8;
  constexpr int M = B * L;           // 4096
  constexpr int DKV = G * 64;        // 512
  constexpr int NQKV = D + 2 * DKV;  // 3072

  char* p = (char*)d_ws;
  bf16*  xb   = (bf16*)p;  p += (size_t)M * D * 2;
  bf16*  wqkv = (bf16*)p;  p += (size_t)NQKV * D * 2;
  bf16*  wob  = (bf16*)p;  p += (size_t)D * D * 2;
  bf16*  qkv  = (bf16*)p;  p += (size_t)M * NQKV * 2;
  bf16*  vtg  = (bf16*)p;  p += (size_t)B * G * 64 * L * 2;
  bf16*  opart = (bf16*)p; p += (size_t)1152 * 128 * 64 * 2;
  float* mpart = (float*)p; p += (size_t)1152 * 128 * 4;
  float* lpart = (float*)p; p += (size_t)1152 * 128 * 4;
  bf16*  ob   = xb;  // xb dead after QKV GEMM

  const bool do_split = ws_size >= (size_t)(p - (char*)d_ws);

  cvt5_kernel<<<dim3(18432), 256, 0, stream>>>(x, Wq, Wk, Wv, Wo, xb, wqkv, wob);

  // fused QKV projection + RoPE epilogue (8-phase 256^2; 192 blocks)
  gemm256<bf16, true><<<dim3((M / 256) * (NQKV / 256)), 512, 0, stream>>>(
      xb, wqkv, qkv, M, NQKV, D, cosb, sinb);

  // V -> swizzled V^T global (consumed by attention via global_load_lds)
  vtr_kernel<<<dim3(L / 64, B * G), 256, 0, stream>>>(qkv + D + DKV, vtg);

  if (do_split) {
    attn_kernel<<<dim3(1600), 256, 0, stream>>>(qkv, qkv + D, vtg, ob,
                                                opart, mpart, lpart, 1152, 6);
    comb_kernel<<<dim3(576), 256, 0, stream>>>(opart, mpart, lpart, ob);
  } else {
    attn_kernel<<<dim3(1024), 256, 0, stream>>>(qkv, qkv + D, vtg, ob,
                                                opart, mpart, lpart, 0, 15);
  }

  // output projection (8-phase 256^2; 128 blocks)
  gemm256<float, false><<<dim3((M / 256) * (D / 256)), 512, 0, stream>>>(
      ob, wob, (float*)d_out, M, D, D, nullptr, nullptr);
}

// Round 14
// 223.805 us; speedup vs baseline: 1.4792x; 1.1364x over previous
//
#include <hip/hip_runtime.h>

typedef __bf16 bf16;
typedef __bf16 bf16x4 __attribute__((ext_vector_type(4)));
typedef __bf16 bf16x8 __attribute__((ext_vector_type(8)));
typedef float  f32x4  __attribute__((ext_vector_type(4)));
typedef float  f32x16 __attribute__((ext_vector_type(16)));

#define GLDS16(gsrc, ldst)                                                    \
  __builtin_amdgcn_global_load_lds(                                          \
      (const __attribute__((address_space(1))) void*)(gsrc),                 \
      (__attribute__((address_space(3))) void*)(ldst), 16, 0, 0)

#define MFMA16(a, b, c) __builtin_amdgcn_mfma_f32_16x16x32_bf16((a), (b), (c), 0, 0, 0)
#define MFMA32(a, b, c) __builtin_amdgcn_mfma_f32_32x32x16_bf16((a), (b), (c), 0, 0, 0)
#define PLSWAP(a, b) asm volatile("v_permlane32_swap_b32 %0, %1" : "+v"(a), "+v"(b))

__device__ inline unsigned pk2(float a, float b) {
  union { bf16 h[2]; unsigned u; } t;
  t.h[0] = (bf16)a; t.h[1] = (bf16)b;
  return t.u;
}
__device__ inline float ex2(float x) { return __builtin_amdgcn_exp2f(x); }

// ---------------- fused f32 -> bf16 convert for all 5 inputs ----------------
__global__ __launch_bounds__(256) void cvt5_kernel(const float* __restrict__ x,
                                                   const float* __restrict__ wq,
                                                   const float* __restrict__ wk,
                                                   const float* __restrict__ wv,
                                                   const float* __restrict__ wo,
                                                   bf16* __restrict__ xb,
                                                   bf16* __restrict__ wqkv,
                                                   bf16* __restrict__ wob) {
  int i = blockIdx.x * 256 + threadIdx.x;
  const float* src; bf16* dst; int off;
  if (i < 2097152)      { src = x;  dst = xb;             off = i; }
  else if (i < 3145728) { src = wq; dst = wqkv;           off = i - 2097152; }
  else if (i < 3407872) { src = wk; dst = wqkv + 4194304; off = i - 3145728; }
  else if (i < 3670016) { src = wv; dst = wqkv + 5242880; off = i - 3407872; }
  else                  { src = wo; dst = wob;            off = i - 3670016; }
  f32x4 f = *(const f32x4*)(src + (size_t)off * 4);
  bf16x4 o4;
#pragma unroll
  for (int j = 0; j < 4; ++j) o4[j] = (bf16)f[j];
  *(bf16x4*)(dst + (size_t)off * 4) = o4;
}

// ---------------- V -> swizzled V^T global ([b][g][64][L]) ----------------
__global__ __launch_bounds__(256) void vtr_kernel(const bf16* __restrict__ v,
                                                  bf16* __restrict__ vt) {
  constexpr int L = 2048, QS = 3072;
  const int kv0 = blockIdx.x * 64;
  const int bg = blockIdx.y;            // b*8+g
  const int tid = threadIdx.x;
  __shared__ bf16 t[64 * 64];

#pragma unroll
  for (int i = 0; i < 2; ++i) {
    int c = tid + 256 * i;
    int kv = c >> 3, e = c & 7;
    bf16x8 row = *(const bf16x8*)(v + (size_t)((bg >> 3) * L + kv0 + kv) * QS +
                                  (bg & 7) * 64 + e * 8);
#pragma unroll
    for (int j = 0; j < 8; ++j)
      t[(8 * e + j) * 64 + (kv ^ (8 * (e ^ j)))] = row[j];
  }
  __syncthreads();

  const int d = tid >> 2, c4 = tid & 3;
  bf16* orow = vt + ((size_t)bg * 64 + d) * L + kv0;
#pragma unroll
  for (int dl = 0; dl < 2; ++dl) {
    int sc = 2 * c4 + dl;
    bf16x8 ch = *(const bf16x8*)&t[d * 64 + 8 * (sc ^ (d >> 3))];
    *(bf16x8*)(orow + 8 * sc) = ch;
  }
}

// ---------------- C = A * B^T  (A: MxK, B: NxK row-major, bf16 MFMA) -------
// m97-class 128x128 structure (R12/R13's 8-phase 256^2 port measured SLOWER at
// these shapes — reverted). 1D grid + XCD-chunked swizzle (T1): chunk shares
// the A-row panel (4 x 512KB fits one XCD L2). ROPE epilogue as before.
template <typename OutT, bool ROPE>
__global__ __launch_bounds__(256) void gemm_bt(const bf16* __restrict__ A,
                                               const bf16* __restrict__ Bm,
                                               OutT* __restrict__ C,
                                               int M, int N, int K,
                                               const float* __restrict__ cosb,
                                               const float* __restrict__ sinb) {
  __shared__ bf16 a_lds[128 * 32];
  __shared__ bf16 b_lds[128 * 32];
  const int tid = threadIdx.x;
  const int w = tid >> 6, lane = tid & 63;
  const int lr = lane & 15, lg = lane >> 4;
  const int wr = w >> 1, wc = w & 1;
  const int nbx = N >> 7;
  const int nwg = (M >> 7) * nbx;
  const int bid = blockIdx.x;
  const int sid = (bid & 7) * (nwg >> 3) + (bid >> 3);   // XCD chunk (nwg%8==0)
  const int m0 = (sid / nbx) << 7, n0 = (sid % nbx) << 7;

  f32x4 acc[4][4];
#pragma unroll
  for (int i = 0; i < 4; ++i)
#pragma unroll
    for (int j = 0; j < 4; ++j) acc[i][j] = f32x4{0.f, 0.f, 0.f, 0.f};

  for (int kt = 0; kt < K; kt += 32) {
#pragma unroll
    for (int i = 0; i < 2; ++i) {
      int c = tid + 256 * i;
      int row = c >> 2, kc = c & 3;
      GLDS16(A  + (size_t)(m0 + row) * K + kt + kc * 8, &a_lds[(w * 64 + 256 * i) * 8]);
      GLDS16(Bm + (size_t)(n0 + row) * K + kt + kc * 8, &b_lds[(w * 64 + 256 * i) * 8]);
    }
    __syncthreads();
    bf16x8 af[4], bfr[4];
#pragma unroll
    for (int t = 0; t < 4; ++t) {
      af[t]  = *(const bf16x8*)&a_lds[(wr * 64 + t * 16 + lr) * 32 + lg * 8];
      bfr[t] = *(const bf16x8*)&b_lds[(wc * 64 + t * 16 + lr) * 32 + lg * 8];
    }
#pragma unroll
    for (int mt = 0; mt < 4; ++mt)
#pragma unroll
      for (int nt = 0; nt < 4; ++nt)
        acc[mt][nt] = MFMA16(af[mt], bfr[nt], acc[mt][nt]);
    __syncthreads();
  }

  const int hb = (n0 + wc * 64) >> 6;                 // head block (wave-uniform)
  const bool dorope = ROPE && (hb < 40);
  const float rsc = (ROPE && hb < 32) ? 0.18033688011112042f : 1.0f;

#pragma unroll
  for (int mt = 0; mt < 4; ++mt)
#pragma unroll
    for (int r = 0; r < 4; ++r) {
      int mm = m0 + wr * 64 + mt * 16 + 4 * lg + r;   // C/D: row = 4*(l>>4)+reg
      float ov[4];
      if (dorope) {
        int l = mm & 2047;
        const float* cp = cosb + l * 64 + lr;
        const float* sp = sinb + l * 64 + lr;
        float a0 = acc[mt][0][r], a1 = acc[mt][1][r];
        float a2 = acc[mt][2][r], a3 = acc[mt][3][r];
        ov[0] = (a0 * cp[0]  - a2 * sp[0])  * rsc;
        ov[1] = (a1 * cp[16] - a3 * sp[16]) * rsc;
        ov[2] = (a2 * cp[32] + a0 * sp[32]) * rsc;
        ov[3] = (a3 * cp[48] + a1 * sp[48]) * rsc;
      } else {
#pragma unroll
        for (int nt = 0; nt < 4; ++nt) ov[nt] = acc[mt][nt][r];
      }
#pragma unroll
      for (int nt = 0; nt < 4; ++nt) {
        int nn = n0 + wc * 64 + nt * 16 + lr;         // col = l&15
        C[(size_t)mm * N + nn] = (OutT)ov[nt];
      }
    }
}

// ---------------- causal GQA flash attention (swapped QK^T, 32x32) ----------
// Split-KV for u>=7 q-tiles (two half-range blocks + combine); longest-first.
__global__ __launch_bounds__(256, 4) void attn_kernel(const bf16* __restrict__ q,
                                                      const bf16* __restrict__ k,
                                                      const bf16* __restrict__ vtg,
                                                      bf16* __restrict__ o,
                                                      bf16* __restrict__ opart,
                                                      float* __restrict__ mpart,
                                                      float* __restrict__ lpart,
                                                      int split_n, int umax) {
  constexpr int L = 2048;
  constexpr int QS = 3072;
  constexpr int OS = 2048;
  const int id = blockIdx.x;
  int bh, u, ts, te, pidx;
  bool split;
  if (id < split_n) {
    bh = id & 63;
    int t = id >> 6;
    u = 15 - (t >> 1);
    int s = t & 1;
    ts = s * (u + 1);
    te = ts + (u + 1);
    pidx = (bh * 9 + (u - 7)) * 2 + s;
    split = true;
  } else {
    int e = id - split_n;
    bh = e & 63;
    u = umax - (e >> 6);
    ts = 0;
    te = 2 * u + 2;
    pidx = 0;
    split = false;
  }
  const int q0 = u * 128;
  const int b = bh >> 5, h = bh & 31, g = h >> 2;
  const int tid = threadIdx.x;
  const int w = tid >> 6, lane = tid & 63;
  const int lc = lane & 31;
  const int H  = lane >> 5;
  const int off4 = 4 * H;
  const int qw = q0 + w * 32;
  const int qg = qw + lc;

  __shared__ bf16 k_lds[2][64 * 64];
  __shared__ bf16 vt_lds[2][64 * 64];

  bf16x8 qf[4];
  {
    const bf16* qrow = q + (size_t)(b * L + qg) * QS + h * 64 + 8 * H;
#pragma unroll
    for (int s = 0; s < 4; ++s) qf[s] = *(const bf16x8*)(qrow + 16 * s);
  }

  f32x16 acc0, acc1;
#pragma unroll
  for (int r = 0; r < 16; ++r) { acc0[r] = 0.f; acc1[r] = 0.f; }
  float m_run = -1e30f, l_run = 0.f;

  const bf16* vbase = vtg + (size_t)(b * 8 + g) * 64 * L;

  auto stageK = [&](int kv0, int buf) {
#pragma unroll
    for (int i = 0; i < 2; ++i) {
      int c = tid + 256 * i;
      int kvr = c >> 3, c8 = c & 7;
      GLDS16(k + (size_t)(b * L + kv0 + kvr) * QS + g * 64 + ((c8 ^ (kvr & 7)) * 8),
             &k_lds[buf][(w * 64 + 256 * i) * 8]);
    }
  };
  auto stageV = [&](int kv0, int buf) {
#pragma unroll
    for (int i = 0; i < 2; ++i) {
      int c = tid + 256 * i;
      GLDS16(vbase + (size_t)(c >> 3) * L + kv0 + (c & 7) * 8,
             &vt_lds[buf][(w * 64 + 256 * i) * 8]);
    }
  };

  stageK(ts * 64, 0);
  stageV(ts * 64, 0);
  __syncthreads();

  for (int it = ts; it < te; ++it) {
    const int cur = (it - ts) & 1;
    const int kv0 = it * 64;
    const bool notlast = (it + 1 < te);
    if (notlast) {
      stageK(kv0 + 64, cur ^ 1);
      stageV(kv0 + 64, cur ^ 1);
    }

    if (kv0 <= qw + 31) {
      f32x16 p0, p1;
#pragma unroll
      for (int r = 0; r < 16; ++r) { p0[r] = 0.f; p1[r] = 0.f; }
      __builtin_amdgcn_s_setprio(1);
#pragma unroll
      for (int s = 0; s < 4; ++s) {
        int ch = ((2 * s + H) ^ (lc & 7)) * 8;
        bf16x8 kf0 = *(const bf16x8*)&k_lds[cur][lc * 64 + ch];
        bf16x8 kf1 = *(const bf16x8*)&k_lds[cur][(32 + lc) * 64 + ch];
        p0 = MFMA32(kf0, qf[s], p0);
        p1 = MFMA32(kf1, qf[s], p1);
      }
      __builtin_amdgcn_s_setprio(0);

      if (kv0 + 63 > qw) {
#pragma unroll
        for (int r = 0; r < 16; ++r) {
          int kvl = kv0 + (r & 3) + 8 * (r >> 2) + off4;
          if (kvl > qg)      p0[r] = -1e30f;
          if (kvl + 32 > qg) p1[r] = -1e30f;
        }
      }

      float mt = -1e30f;
#pragma unroll
      for (int r = 0; r < 16; ++r) mt = fmaxf(mt, fmaxf(p0[r], p1[r]));
      mt = fmaxf(mt, __shfl_xor(mt, 32));
      const int defer = __all(mt <= m_run + 11.0f);
      float alpha = 1.f;
      if (!defer) {
        float mn = fmaxf(m_run, mt);
        alpha = ex2(m_run - mn);
        m_run = mn;
      }
      float ls = 0.f;
#pragma unroll
      for (int r = 0; r < 16; ++r) {
        p0[r] = ex2(p0[r] - m_run);
        p1[r] = ex2(p1[r] - m_run);
        ls += p0[r] + p1[r];
      }
      ls += __shfl_xor(ls, 32);
      l_run = l_run * alpha + ls;
      if (!defer) {
#pragma unroll
        for (int r = 0; r < 16; ++r) {
          float aq = __shfl(alpha, ((r & 3) + 8 * (r >> 2)) + off4);
          acc0[r] *= aq;
          acc1[r] *= aq;
        }
      }

      unsigned A[16];
#pragma unroll
      for (int i = 0; i < 8; ++i) {
        A[i]     = pk2(p0[2 * i], p0[2 * i + 1]);
        A[8 + i] = pk2(p1[2 * i], p1[2 * i + 1]);
      }
#pragma unroll
      for (int base = 0; base < 16; base += 4) {
        PLSWAP(A[base],     A[base + 2]);
        PLSWAP(A[base + 1], A[base + 3]);
      }

      __builtin_amdgcn_s_setprio(1);
#pragma unroll
      for (int sp = 0; sp < 4; ++sp) {
        union { unsigned u[4]; bf16x8 v8; } pa;
#pragma unroll
        for (int jx = 0; jx < 4; ++jx) pa.u[jx] = A[4 * sp + jx];
        int ch = ((2 * sp + H) ^ (lc & 7)) * 8;
        bf16x8 vf0 = *(const bf16x8*)&vt_lds[cur][lc * 64 + ch];
        bf16x8 vf1 = *(const bf16x8*)&vt_lds[cur][(32 + lc) * 64 + ch];
        acc0 = MFMA32(pa.v8, vf0, acc0);
        acc1 = MFMA32(pa.v8, vf1, acc1);
      }
      __builtin_amdgcn_s_setprio(0);
    }

    __syncthreads();
  }

  if (split) {
    bf16* op = opart + (size_t)pidx * (128 * 64);
#pragma unroll
    for (int r = 0; r < 16; ++r) {
      int qrow = w * 32 + (r & 3) + 8 * (r >> 2) + off4;
      op[qrow * 64 + lc]      = (bf16)acc0[r];
      op[qrow * 64 + 32 + lc] = (bf16)acc1[r];
    }
    if (H == 0) {
      mpart[(size_t)pidx * 128 + w * 32 + lc] = m_run;
      lpart[(size_t)pidx * 128 + w * 32 + lc] = l_run;
    }
  } else {
#pragma unroll
    for (int r = 0; r < 16; ++r) {
      int qrow = (r & 3) + 8 * (r >> 2) + off4;
      float lq = __shfl(l_run, qrow);
      float inv = 1.f / lq;
      size_t orow = (size_t)(b * L + qw + qrow) * OS + h * 64;
      o[orow + lc]      = (bf16)(acc0[r] * inv);
      o[orow + 32 + lc] = (bf16)(acc1[r] * inv);
    }
  }
}

// ---------------- combine split-KV partials ----------------
__global__ __launch_bounds__(256) void comb_kernel(const bf16* __restrict__ opart,
                                                   const float* __restrict__ mpart,
                                                   const float* __restrict__ lpart,
                                                   bf16* __restrict__ o) {
  constexpr int L = 2048, OS = 2048;
  const int blk = blockIdx.x;
  const int bh = blk / 9, uu = blk % 9, u = uu + 7;
  const int b = bh >> 5, h = bh & 31;
  const int q0 = u * 128;
  const int t = threadIdx.x;
  const int row = t >> 1, dh = (t & 1) * 32;

  const size_t s0 = (size_t)blk * 2, s1 = s0 + 1;
  float m0 = mpart[s0 * 128 + row], m1 = mpart[s1 * 128 + row];
  float l0 = lpart[s0 * 128 + row], l1 = lpart[s1 * 128 + row];
  float m = fmaxf(m0, m1);
  float w0 = ex2(m0 - m), w1 = ex2(m1 - m);
  float inv = 1.f / (l0 * w0 + l1 * w1);

  const bf16* O0 = opart + s0 * (128 * 64) + row * 64 + dh;
  const bf16* O1 = opart + s1 * (128 * 64) + row * 64 + dh;
  bf16* orow = o + (size_t)(b * L + q0 + row) * OS + h * 64 + dh;
#pragma unroll
  for (int j = 0; j < 4; ++j) {
    bf16x8 a = *(const bf16x8*)(O0 + 8 * j);
    bf16x8 c = *(const bf16x8*)(O1 + 8 * j);
    bf16x8 r;
#pragma unroll
    for (int e = 0; e < 8; ++e)
      r[e] = (bf16)(((float)a[e] * w0 + (float)c[e] * w1) * inv);
    *(bf16x8*)(orow + 8 * j) = r;
  }
}

extern "C" void kernel_launch(void* const* d_in, const int* in_sizes, int n_in,
                              void* d_out, int out_size, void* d_ws, size_t ws_size,
                              hipStream_t stream) {
  (void)in_sizes; (void)n_in; (void)out_size;
  const float* x    = (const float*)d_in[0];
  const float* cosb = (const float*)d_in[1];
  const float* sinb = (const float*)d_in[2];
  const float* Wq   = (const float*)d_in[3];
  const float* Wk   = (const float*)d_in[4];
  const float* Wv   = (const float*)d_in[5];
  const float* Wo   = (const float*)d_in[6];

  constexpr int B = 2, L = 2048, D = 2048, H = 32, G = 8;
  constexpr int M = B * L;           // 4096
  constexpr int DKV = G * 64;        // 512
  constexpr int NQKV = D + 2 * DKV;  // 3072

  char* p = (char*)d_ws;
  bf16*  xb   = (bf16*)p;  p += (size_t)M * D * 2;
  bf16*  wqkv = (bf16*)p;  p += (size_t)NQKV * D * 2;
  bf16*  wob  = (bf16*)p;  p += (size_t)D * D * 2;
  bf16*  qkv  = (bf16*)p;  p += (size_t)M * NQKV * 2;
  bf16*  vtg  = (bf16*)p;  p += (size_t)B * G * 64 * L * 2;
  bf16*  opart = (bf16*)p; p += (size_t)1152 * 128 * 64 * 2;
  float* mpart = (float*)p; p += (size_t)1152 * 128 * 4;
  float* lpart = (float*)p; p += (size_t)1152 * 128 * 4;
  bf16*  ob   = xb;  // xb dead after QKV GEMM

  const bool do_split = ws_size >= (size_t)(p - (char*)d_ws);

  cvt5_kernel<<<dim3(18432), 256, 0, stream>>>(x, Wq, Wk, Wv, Wo, xb, wqkv, wob);

  // fused QKV projection + RoPE epilogue (m97 structure, XCD-chunked 1D grid)
  gemm_bt<bf16, true><<<dim3((NQKV / 128) * (M / 128)), 256, 0, stream>>>(
      xb, wqkv, qkv, M, NQKV, D, cosb, sinb);

  // V -> swizzled V^T global (consumed by attention via global_load_lds)
  vtr_kernel<<<dim3(L / 64, B * G), 256, 0, stream>>>(qkv + D + DKV, vtg);

  if (do_split) {
    attn_kernel<<<dim3(1600), 256, 0, stream>>>(qkv, qkv + D, vtg, ob,
                                                opart, mpart, lpart, 1152, 6);
    comb_kernel<<<dim3(576), 256, 0, stream>>>(opart, mpart, lpart, ob);
  } else {
    attn_kernel<<<dim3(1024), 256, 0, stream>>>(qkv, qkv + D, vtg, ob,
                                                opart, mpart, lpart, 0, 15);
  }

  // output projection (m97 structure, XCD-chunked 1D grid)
  gemm_bt<float, false><<<dim3((D / 128) * (M / 128)), 256, 0, stream>>>(
      ob, wob, (float*)d_out, M, D, D, nullptr, nullptr);
}

// Round 15
// 223.648 us; speedup vs baseline: 1.4803x; 1.0007x over previous
//
#include <hip/hip_runtime.h>

typedef __bf16 bf16;
typedef __bf16 bf16x4 __attribute__((ext_vector_type(4)));
typedef __bf16 bf16x8 __attribute__((ext_vector_type(8)));
typedef float  f32x4  __attribute__((ext_vector_type(4)));
typedef float  f32x16 __attribute__((ext_vector_type(16)));

#define GLDS16(gsrc, ldst)                                                    \
  __builtin_amdgcn_global_load_lds(                                          \
      (const __attribute__((address_space(1))) void*)(gsrc),                 \
      (__attribute__((address_space(3))) void*)(ldst), 16, 0, 0)

#define MFMA16(a, b, c) __builtin_amdgcn_mfma_f32_16x16x32_bf16((a), (b), (c), 0, 0, 0)
#define MFMA32(a, b, c) __builtin_amdgcn_mfma_f32_32x32x16_bf16((a), (b), (c), 0, 0, 0)
#define PLSWAP(a, b) asm volatile("v_permlane32_swap_b32 %0, %1" : "+v"(a), "+v"(b))

__device__ inline unsigned pk2(float a, float b) {
  union { bf16 h[2]; unsigned u; } t;
  t.h[0] = (bf16)a; t.h[1] = (bf16)b;
  return t.u;
}
__device__ inline float ex2(float x) { return __builtin_amdgcn_exp2f(x); }

// ---------------- fused f32 -> bf16 convert for all 5 inputs ----------------
__global__ __launch_bounds__(256) void cvt5_kernel(const float* __restrict__ x,
                                                   const float* __restrict__ wq,
                                                   const float* __restrict__ wk,
                                                   const float* __restrict__ wv,
                                                   const float* __restrict__ wo,
                                                   bf16* __restrict__ xb,
                                                   bf16* __restrict__ wqkv,
                                                   bf16* __restrict__ wob) {
  int i = blockIdx.x * 256 + threadIdx.x;
  const float* src; bf16* dst; int off;
  if (i < 2097152)      { src = x;  dst = xb;             off = i; }
  else if (i < 3145728) { src = wq; dst = wqkv;           off = i - 2097152; }
  else if (i < 3407872) { src = wk; dst = wqkv + 4194304; off = i - 3145728; }
  else if (i < 3670016) { src = wv; dst = wqkv + 5242880; off = i - 3407872; }
  else                  { src = wo; dst = wob;            off = i - 3670016; }
  f32x4 f = *(const f32x4*)(src + (size_t)off * 4);
  bf16x4 o4;
#pragma unroll
  for (int j = 0; j < 4; ++j) o4[j] = (bf16)f[j];
  *(bf16x4*)(dst + (size_t)off * 4) = o4;
}

// ---------------- V -> swizzled V^T global ([b][g][64][L]) ----------------
__global__ __launch_bounds__(256) void vtr_kernel(const bf16* __restrict__ v,
                                                  bf16* __restrict__ vt) {
  constexpr int L = 2048, QS = 3072;
  const int kv0 = blockIdx.x * 64;
  const int bg = blockIdx.y;            // b*8+g
  const int tid = threadIdx.x;
  __shared__ bf16 t[64 * 64];

#pragma unroll
  for (int i = 0; i < 2; ++i) {
    int c = tid + 256 * i;
    int kv = c >> 3, e = c & 7;
    bf16x8 row = *(const bf16x8*)(v + (size_t)((bg >> 3) * L + kv0 + kv) * QS +
                                  (bg & 7) * 64 + e * 8);
#pragma unroll
    for (int j = 0; j < 8; ++j)
      t[(8 * e + j) * 64 + (kv ^ (8 * (e ^ j)))] = row[j];
  }
  __syncthreads();

  const int d = tid >> 2, c4 = tid & 3;
  bf16* orow = vt + ((size_t)bg * 64 + d) * L + kv0;
#pragma unroll
  for (int dl = 0; dl < 2; ++dl) {
    int sc = 2 * c4 + dl;
    bf16x8 ch = *(const bf16x8*)&t[d * 64 + 8 * (sc ^ (d >> 3))];
    *(bf16x8*)(orow + 8 * sc) = ch;
  }
}

// ---------------- C = A * B^T  (A: MxK, B: NxK row-major, bf16 MFMA) -------
// m97-class 128x128 structure, XCD-chunked 1D grid (T1). R15: staging
// addresses strength-reduced to incremented pointers (VALUBusy 47% was
// dominated by per-K-step 64-bit address recompute). ROPE epilogue as before.
template <typename OutT, bool ROPE>
__global__ __launch_bounds__(256) void gemm_bt(const bf16* __restrict__ A,
                                               const bf16* __restrict__ Bm,
                                               OutT* __restrict__ C,
                                               int M, int N, int K,
                                               const float* __restrict__ cosb,
                                               const float* __restrict__ sinb) {
  __shared__ bf16 a_lds[128 * 32];
  __shared__ bf16 b_lds[128 * 32];
  const int tid = threadIdx.x;
  const int w = tid >> 6, lane = tid & 63;
  const int lr = lane & 15, lg = lane >> 4;
  const int wr = w >> 1, wc = w & 1;
  const int nbx = N >> 7;
  const int nwg = (M >> 7) * nbx;
  const int bid = blockIdx.x;
  const int sid = (bid & 7) * (nwg >> 3) + (bid >> 3);   // XCD chunk (nwg%8==0)
  const int m0 = (sid / nbx) << 7, n0 = (sid % nbx) << 7;

  f32x4 acc[4][4];
#pragma unroll
  for (int i = 0; i < 4; ++i)
#pragma unroll
    for (int j = 0; j < 4; ++j) acc[i][j] = f32x4{0.f, 0.f, 0.f, 0.f};

  // staging pointers (hoisted; advanced by 32 elems per K-step)
  const int srow = tid >> 2, skc = (tid & 3) * 8;
  const bf16* ap0 = A  + (size_t)(m0 + srow) * K + skc;
  const bf16* ap1 = A  + (size_t)(m0 + srow + 64) * K + skc;
  const bf16* bp0 = Bm + (size_t)(n0 + srow) * K + skc;
  const bf16* bp1 = Bm + (size_t)(n0 + srow + 64) * K + skc;
  bf16* const lA0 = &a_lds[w * 512];
  bf16* const lA1 = &a_lds[w * 512 + 2048];
  bf16* const lB0 = &b_lds[w * 512];
  bf16* const lB1 = &b_lds[w * 512 + 2048];

  for (int kt = 0; kt < K; kt += 32) {
    GLDS16(ap0, lA0);
    GLDS16(ap1, lA1);
    GLDS16(bp0, lB0);
    GLDS16(bp1, lB1);
    ap0 += 32; ap1 += 32; bp0 += 32; bp1 += 32;
    __syncthreads();
    bf16x8 af[4], bfr[4];
#pragma unroll
    for (int t = 0; t < 4; ++t) {
      af[t]  = *(const bf16x8*)&a_lds[(wr * 64 + t * 16 + lr) * 32 + lg * 8];
      bfr[t] = *(const bf16x8*)&b_lds[(wc * 64 + t * 16 + lr) * 32 + lg * 8];
    }
#pragma unroll
    for (int mt = 0; mt < 4; ++mt)
#pragma unroll
      for (int nt = 0; nt < 4; ++nt)
        acc[mt][nt] = MFMA16(af[mt], bfr[nt], acc[mt][nt]);
    __syncthreads();
  }

  const int hb = (n0 + wc * 64) >> 6;                 // head block (wave-uniform)
  const bool dorope = ROPE && (hb < 40);
  const float rsc = (ROPE && hb < 32) ? 0.18033688011112042f : 1.0f;

#pragma unroll
  for (int mt = 0; mt < 4; ++mt)
#pragma unroll
    for (int r = 0; r < 4; ++r) {
      int mm = m0 + wr * 64 + mt * 16 + 4 * lg + r;   // C/D: row = 4*(l>>4)+reg
      float ov[4];
      if (dorope) {
        int l = mm & 2047;
        const float* cp = cosb + l * 64 + lr;
        const float* sp = sinb + l * 64 + lr;
        float a0 = acc[mt][0][r], a1 = acc[mt][1][r];
        float a2 = acc[mt][2][r], a3 = acc[mt][3][r];
        ov[0] = (a0 * cp[0]  - a2 * sp[0])  * rsc;
        ov[1] = (a1 * cp[16] - a3 * sp[16]) * rsc;
        ov[2] = (a2 * cp[32] + a0 * sp[32]) * rsc;
        ov[3] = (a3 * cp[48] + a1 * sp[48]) * rsc;
      } else {
#pragma unroll
        for (int nt = 0; nt < 4; ++nt) ov[nt] = acc[mt][nt][r];
      }
#pragma unroll
      for (int nt = 0; nt < 4; ++nt) {
        int nn = n0 + wc * 64 + nt * 16 + lr;         // col = l&15
        C[(size_t)mm * N + nn] = (OutT)ov[nt];
      }
    }
}

// ---------------- causal GQA flash attention (swapped QK^T, 32x32) ----------
// Split-KV for u>=7 q-tiles (two half-range blocks + combine); longest-first.
// R15: staging addresses strength-reduced to incremented pointers.
__global__ __launch_bounds__(256, 4) void attn_kernel(const bf16* __restrict__ q,
                                                      const bf16* __restrict__ k,
                                                      const bf16* __restrict__ vtg,
                                                      bf16* __restrict__ o,
                                                      bf16* __restrict__ opart,
                                                      float* __restrict__ mpart,
                                                      float* __restrict__ lpart,
                                                      int split_n, int umax) {
  constexpr int L = 2048;
  constexpr int QS = 3072;
  constexpr int OS = 2048;
  const int id = blockIdx.x;
  int bh, u, ts, te, pidx;
  bool split;
  if (id < split_n) {
    bh = id & 63;
    int t = id >> 6;
    u = 15 - (t >> 1);
    int s = t & 1;
    ts = s * (u + 1);
    te = ts + (u + 1);
    pidx = (bh * 9 + (u - 7)) * 2 + s;
    split = true;
  } else {
    int e = id - split_n;
    bh = e & 63;
    u = umax - (e >> 6);
    ts = 0;
    te = 2 * u + 2;
    pidx = 0;
    split = false;
  }
  const int q0 = u * 128;
  const int b = bh >> 5, h = bh & 31, g = h >> 2;
  const int tid = threadIdx.x;
  const int w = tid >> 6, lane = tid & 63;
  const int lc = lane & 31;
  const int H  = lane >> 5;
  const int off4 = 4 * H;
  const int qw = q0 + w * 32;
  const int qg = qw + lc;

  __shared__ bf16 k_lds[2][64 * 64];
  __shared__ bf16 vt_lds[2][64 * 64];

  bf16x8 qf[4];
  {
    const bf16* qrow = q + (size_t)(b * L + qg) * QS + h * 64 + 8 * H;
#pragma unroll
    for (int s = 0; s < 4; ++s) qf[s] = *(const bf16x8*)(qrow + 16 * s);
  }

  f32x16 acc0, acc1;
#pragma unroll
  for (int r = 0; r < 16; ++r) { acc0[r] = 0.f; acc1[r] = 0.f; }
  float m_run = -1e30f, l_run = 0.f;

  const bf16* vbase = vtg + (size_t)(b * 8 + g) * 64 * L;

  // staging pointers (hoisted; advance per staged tile)
  const int kvr = tid >> 3, c8 = tid & 7;
  const bf16* kp0 = k + (size_t)(b * L + ts * 64 + kvr) * QS + g * 64 + ((c8 ^ (kvr & 7)) * 8);
  const bf16* kp1 = kp0 + (size_t)32 * QS;
  const bf16* vp0 = vbase + (size_t)kvr * L + ts * 64 + c8 * 8;
  const bf16* vp1 = vp0 + (size_t)32 * L;

  auto stageK = [&](int buf) {
    GLDS16(kp0, &k_lds[buf][w * 512]);
    GLDS16(kp1, &k_lds[buf][w * 512 + 2048]);
    kp0 += (size_t)64 * QS; kp1 += (size_t)64 * QS;
  };
  auto stageV = [&](int buf) {
    GLDS16(vp0, &vt_lds[buf][w * 512]);
    GLDS16(vp1, &vt_lds[buf][w * 512 + 2048]);
    vp0 += 64; vp1 += 64;
  };

  stageK(0);
  stageV(0);
  __syncthreads();

  for (int it = ts; it < te; ++it) {
    const int cur = (it - ts) & 1;
    const int kv0 = it * 64;
    const bool notlast = (it + 1 < te);
    if (notlast) {
      stageK(cur ^ 1);
      stageV(cur ^ 1);
    }

    if (kv0 <= qw + 31) {
      f32x16 p0, p1;
#pragma unroll
      for (int r = 0; r < 16; ++r) { p0[r] = 0.f; p1[r] = 0.f; }
      __builtin_amdgcn_s_setprio(1);
#pragma unroll
      for (int s = 0; s < 4; ++s) {
        int ch = ((2 * s + H) ^ (lc & 7)) * 8;
        bf16x8 kf0 = *(const bf16x8*)&k_lds[cur][lc * 64 + ch];
        bf16x8 kf1 = *(const bf16x8*)&k_lds[cur][(32 + lc) * 64 + ch];
        p0 = MFMA32(kf0, qf[s], p0);
        p1 = MFMA32(kf1, qf[s], p1);
      }
      __builtin_amdgcn_s_setprio(0);

      if (kv0 + 63 > qw) {
#pragma unroll
        for (int r = 0; r < 16; ++r) {
          int kvl = kv0 + (r & 3) + 8 * (r >> 2) + off4;
          if (kvl > qg)      p0[r] = -1e30f;
          if (kvl + 32 > qg) p1[r] = -1e30f;
        }
      }

      float mt = -1e30f;
#pragma unroll
      for (int r = 0; r < 16; ++r) mt = fmaxf(mt, fmaxf(p0[r], p1[r]));
      mt = fmaxf(mt, __shfl_xor(mt, 32));
      const int defer = __all(mt <= m_run + 11.0f);
      float alpha = 1.f;
      if (!defer) {
        float mn = fmaxf(m_run, mt);
        alpha = ex2(m_run - mn);
        m_run = mn;
      }
      float ls = 0.f;
#pragma unroll
      for (int r = 0; r < 16; ++r) {
        p0[r] = ex2(p0[r] - m_run);
        p1[r] = ex2(p1[r] - m_run);
        ls += p0[r] + p1[r];
      }
      ls += __shfl_xor(ls, 32);
      l_run = l_run * alpha + ls;
      if (!defer) {
#pragma unroll
        for (int r = 0; r < 16; ++r) {
          float aq = __shfl(alpha, ((r & 3) + 8 * (r >> 2)) + off4);
          acc0[r] *= aq;
          acc1[r] *= aq;
        }
      }

      unsigned A[16];
#pragma unroll
      for (int i = 0; i < 8; ++i) {
        A[i]     = pk2(p0[2 * i], p0[2 * i + 1]);
        A[8 + i] = pk2(p1[2 * i], p1[2 * i + 1]);
      }
#pragma unroll
      for (int base = 0; base < 16; base += 4) {
        PLSWAP(A[base],     A[base + 2]);
        PLSWAP(A[base + 1], A[base + 3]);
      }

      __builtin_amdgcn_s_setprio(1);
#pragma unroll
      for (int sp = 0; sp < 4; ++sp) {
        union { unsigned u[4]; bf16x8 v8; } pa;
#pragma unroll
        for (int jx = 0; jx < 4; ++jx) pa.u[jx] = A[4 * sp + jx];
        int ch = ((2 * sp + H) ^ (lc & 7)) * 8;
        bf16x8 vf0 = *(const bf16x8*)&vt_lds[cur][lc * 64 + ch];
        bf16x8 vf1 = *(const bf16x8*)&vt_lds[cur][(32 + lc) * 64 + ch];
        acc0 = MFMA32(pa.v8, vf0, acc0);
        acc1 = MFMA32(pa.v8, vf1, acc1);
      }
      __builtin_amdgcn_s_setprio(0);
    }

    __syncthreads();
  }

  if (split) {
    bf16* op = opart + (size_t)pidx * (128 * 64);
#pragma unroll
    for (int r = 0; r < 16; ++r) {
      int qrow = w * 32 + (r & 3) + 8 * (r >> 2) + off4;
      op[qrow * 64 + lc]      = (bf16)acc0[r];
      op[qrow * 64 + 32 + lc] = (bf16)acc1[r];
    }
    if (H == 0) {
      mpart[(size_t)pidx * 128 + w * 32 + lc] = m_run;
      lpart[(size_t)pidx * 128 + w * 32 + lc] = l_run;
    }
  } else {
#pragma unroll
    for (int r = 0; r < 16; ++r) {
      int qrow = (r & 3) + 8 * (r >> 2) + off4;
      float lq = __shfl(l_run, qrow);
      float inv = 1.f / lq;
      size_t orow = (size_t)(b * L + qw + qrow) * OS + h * 64;
      o[orow + lc]      = (bf16)(acc0[r] * inv);
      o[orow + 32 + lc] = (bf16)(acc1[r] * inv);
    }
  }
}

// ---------------- combine split-KV partials ----------------
__global__ __launch_bounds__(256) void comb_kernel(const bf16* __restrict__ opart,
                                                   const float* __restrict__ mpart,
                                                   const float* __restrict__ lpart,
                                                   bf16* __restrict__ o) {
  constexpr int L = 2048, OS = 2048;
  const int blk = blockIdx.x;
  const int bh = blk / 9, uu = blk % 9, u = uu + 7;
  const int b = bh >> 5, h = bh & 31;
  const int q0 = u * 128;
  const int t = threadIdx.x;
  const int row = t >> 1, dh = (t & 1) * 32;

  const size_t s0 = (size_t)blk * 2, s1 = s0 + 1;
  float m0 = mpart[s0 * 128 + row], m1 = mpart[s1 * 128 + row];
  float l0 = lpart[s0 * 128 + row], l1 = lpart[s1 * 128 + row];
  float m = fmaxf(m0, m1);
  float w0 = ex2(m0 - m), w1 = ex2(m1 - m);
  float inv = 1.f / (l0 * w0 + l1 * w1);

  const bf16* O0 = opart + s0 * (128 * 64) + row * 64 + dh;
  const bf16* O1 = opart + s1 * (128 * 64) + row * 64 + dh;
  bf16* orow = o + (size_t)(b * L + q0 + row) * OS + h * 64 + dh;
#pragma unroll
  for (int j = 0; j < 4; ++j) {
    bf16x8 a = *(const bf16x8*)(O0 + 8 * j);
    bf16x8 c = *(const bf16x8*)(O1 + 8 * j);
    bf16x8 r;
#pragma unroll
    for (int e = 0; e < 8; ++e)
      r[e] = (bf16)(((float)a[e] * w0 + (float)c[e] * w1) * inv);
    *(bf16x8*)(orow + 8 * j) = r;
  }
}

extern "C" void kernel_launch(void* const* d_in, const int* in_sizes, int n_in,
                              void* d_out, int out_size, void* d_ws, size_t ws_size,
                              hipStream_t stream) {
  (void)in_sizes; (void)n_in; (void)out_size;
  const float* x    = (const float*)d_in[0];
  const float* cosb = (const float*)d_in[1];
  const float* sinb = (const float*)d_in[2];
  const float* Wq   = (const float*)d_in[3];
  const float* Wk   = (const float*)d_in[4];
  const float* Wv   = (const float*)d_in[5];
  const float* Wo   = (const float*)d_in[6];

  constexpr int B = 2, L = 2048, D = 2048, H = 32, G = 8;
  constexpr int M = B * L;           // 4096
  constexpr int DKV = G * 64;        // 512
  constexpr int NQKV = D + 2 * DKV;  // 3072

  char* p = (char*)d_ws;
  bf16*  xb   = (bf16*)p;  p += (size_t)M * D * 2;
  bf16*  wqkv = (bf16*)p;  p += (size_t)NQKV * D * 2;
  bf16*  wob  = (bf16*)p;  p += (size_t)D * D * 2;
  bf16*  qkv  = (bf16*)p;  p += (size_t)M * NQKV * 2;
  bf16*  vtg  = (bf16*)p;  p += (size_t)B * G * 64 * L * 2;
  bf16*  opart = (bf16*)p; p += (size_t)1152 * 128 * 64 * 2;
  float* mpart = (float*)p; p += (size_t)1152 * 128 * 4;
  float* lpart = (float*)p; p += (size_t)1152 * 128 * 4;
  bf16*  ob   = xb;  // xb dead after QKV GEMM

  const bool do_split = ws_size >= (size_t)(p - (char*)d_ws);

  cvt5_kernel<<<dim3(18432), 256, 0, stream>>>(x, Wq, Wk, Wv, Wo, xb, wqkv, wob);

  // fused QKV projection + RoPE epilogue (m97 structure, XCD-chunked 1D grid)
  gemm_bt<bf16, true><<<dim3((NQKV / 128) * (M / 128)), 256, 0, stream>>>(
      xb, wqkv, qkv, M, NQKV, D, cosb, sinb);

  // V -> swizzled V^T global (consumed by attention via global_load_lds)
  vtr_kernel<<<dim3(L / 64, B * G), 256, 0, stream>>>(qkv + D + DKV, vtg);

  if (do_split) {
    attn_kernel<<<dim3(1600), 256, 0, stream>>>(qkv, qkv + D, vtg, ob,
                                                opart, mpart, lpart, 1152, 6);
    comb_kernel<<<dim3(576), 256, 0, stream>>>(opart, mpart, lpart, ob);
  } else {
    attn_kernel<<<dim3(1024), 256, 0, stream>>>(qkv, qkv + D, vtg, ob,
                                                opart, mpart, lpart, 0, 15);
  }

  // output projection (m97 structure, XCD-chunked 1D grid)
  gemm_bt<float, false><<<dim3((D / 128) * (M / 128)), 256, 0, stream>>>(
      ob, wob, (float*)d_out, M, D, D, nullptr, nullptr);
}

// Round 16
// 223.038 us; speedup vs baseline: 1.4843x; 1.0027x over previous
//
#include <hip/hip_runtime.h>

typedef __bf16 bf16;
typedef __bf16 bf16x4 __attribute__((ext_vector_type(4)));
typedef __bf16 bf16x8 __attribute__((ext_vector_type(8)));
typedef float  f32x4  __attribute__((ext_vector_type(4)));
typedef float  f32x16 __attribute__((ext_vector_type(16)));

#define GLDS16(gsrc, ldst)                                                    \
  __builtin_amdgcn_global_load_lds(                                          \
      (const __attribute__((address_space(1))) void*)(gsrc),                 \
      (__attribute__((address_space(3))) void*)(ldst), 16, 0, 0)

#define MFMA16(a, b, c) __builtin_amdgcn_mfma_f32_16x16x32_bf16((a), (b), (c), 0, 0, 0)
#define MFMA32(a, b, c) __builtin_amdgcn_mfma_f32_32x32x16_bf16((a), (b), (c), 0, 0, 0)
#define PLSWAP(a, b) asm volatile("v_permlane32_swap_b32 %0, %1" : "+v"(a), "+v"(b))

__device__ inline unsigned pk2(float a, float b) {
  union { bf16 h[2]; unsigned u; } t;
  t.h[0] = (bf16)a; t.h[1] = (bf16)b;
  return t.u;
}
__device__ inline float ex2(float x) { return __builtin_amdgcn_exp2f(x); }

// ---------------- fused f32 -> bf16 convert for all 5 inputs ----------------
__global__ __launch_bounds__(256) void cvt5_kernel(const float* __restrict__ x,
                                                   const float* __restrict__ wq,
                                                   const float* __restrict__ wk,
                                                   const float* __restrict__ wv,
                                                   const float* __restrict__ wo,
                                                   bf16* __restrict__ xb,
                                                   bf16* __restrict__ wqkv,
                                                   bf16* __restrict__ wob) {
  int i = blockIdx.x * 256 + threadIdx.x;
  const float* src; bf16* dst; int off;
  if (i < 2097152)      { src = x;  dst = xb;             off = i; }
  else if (i < 3145728) { src = wq; dst = wqkv;           off = i - 2097152; }
  else if (i < 3407872) { src = wk; dst = wqkv + 4194304; off = i - 3145728; }
  else if (i < 3670016) { src = wv; dst = wqkv + 5242880; off = i - 3407872; }
  else                  { src = wo; dst = wob;            off = i - 3670016; }
  f32x4 f = *(const f32x4*)(src + (size_t)off * 4);
  bf16x4 o4;
#pragma unroll
  for (int j = 0; j < 4; ++j) o4[j] = (bf16)f[j];
  *(bf16x4*)(dst + (size_t)off * 4) = o4;
}

// ---------------- V -> swizzled V^T global ([b][g][64][L]) ----------------
__global__ __launch_bounds__(256) void vtr_kernel(const bf16* __restrict__ v,
                                                  bf16* __restrict__ vt) {
  constexpr int L = 2048, QS = 3072;
  const int kv0 = blockIdx.x * 64;
  const int bg = blockIdx.y;            // b*8+g
  const int tid = threadIdx.x;
  __shared__ bf16 t[64 * 64];

#pragma unroll
  for (int i = 0; i < 2; ++i) {
    int c = tid + 256 * i;
    int kv = c >> 3, e = c & 7;
    bf16x8 row = *(const bf16x8*)(v + (size_t)((bg >> 3) * L + kv0 + kv) * QS +
                                  (bg & 7) * 64 + e * 8);
#pragma unroll
    for (int j = 0; j < 8; ++j)
      t[(8 * e + j) * 64 + (kv ^ (8 * (e ^ j)))] = row[j];
  }
  __syncthreads();

  const int d = tid >> 2, c4 = tid & 3;
  bf16* orow = vt + ((size_t)bg * 64 + d) * L + kv0;
#pragma unroll
  for (int dl = 0; dl < 2; ++dl) {
    int sc = 2 * c4 + dl;
    bf16x8 ch = *(const bf16x8*)&t[d * 64 + 8 * (sc ^ (d >> 3))];
    *(bf16x8*)(orow + 8 * sc) = ch;
  }
}

// ---------------- C = A * B^T  (A: MxK, B: NxK row-major, bf16 MFMA) -------
// m97-class 128x128 tile, BK=64 (R16): halves the barrier count per unit K —
// the ~20% structural stall of this loop is the per-barrier vmcnt drain.
// LDS 32KB (occupancy unchanged, VGPR-bound 3 blocks/CU). Row stride is now
// 128B (the G4 pathology), so tiles use the attn-proven chunk-XOR swizzle:
// store chunk c^(row&7) via pre-swizzled GLOBAL source (rule #21), read chunk
// (4kc+lg)^(row&7) -> exact b128 8-access/bank floor (audit in journal).
// XCD-chunked 1D grid (T1). ROPE epilogue unchanged.
template <typename OutT, bool ROPE>
__global__ __launch_bounds__(256) void gemm_bt(const bf16* __restrict__ A,
                                               const bf16* __restrict__ Bm,
                                               OutT* __restrict__ C,
                                               int M, int N, int K,
                                               const float* __restrict__ cosb,
                                               const float* __restrict__ sinb) {
  __shared__ bf16 a_lds[128 * 64];
  __shared__ bf16 b_lds[128 * 64];
  const int tid = threadIdx.x;
  const int w = tid >> 6, lane = tid & 63;
  const int lr = lane & 15, lg = lane >> 4;
  const int wr = w >> 1, wc = w & 1;
  const int nbx = N >> 7;
  const int nwg = (M >> 7) * nbx;
  const int bid = blockIdx.x;
  const int sid = (bid & 7) * (nwg >> 3) + (bid >> 3);   // XCD chunk (nwg%8==0)
  const int m0 = (sid / nbx) << 7, n0 = (sid % nbx) << 7;

  f32x4 acc[4][4];
#pragma unroll
  for (int i = 0; i < 4; ++i)
#pragma unroll
    for (int j = 0; j < 4; ++j) acc[i][j] = f32x4{0.f, 0.f, 0.f, 0.f};

  // staging pointers: 4 chunks per matrix per thread (1024 chunks / 256 thr).
  // ci = tid + 256*i -> row = ci>>3, chunk c = ci&7, source chunk c^(row&7).
  const bf16* ap[4];
  const bf16* bp[4];
#pragma unroll
  for (int i = 0; i < 4; ++i) {
    int ci = tid + 256 * i;
    int row = ci >> 3, c = ci & 7;
    int cs = c ^ (row & 7);
    ap[i] = A  + (size_t)(m0 + row) * K + cs * 8;
    bp[i] = Bm + (size_t)(n0 + row) * K + cs * 8;
  }

  for (int kt = 0; kt < K; kt += 64) {
#pragma unroll
    for (int i = 0; i < 4; ++i) {
      GLDS16(ap[i], &a_lds[w * 512 + i * 2048]);
      GLDS16(bp[i], &b_lds[w * 512 + i * 2048]);
      ap[i] += 64; bp[i] += 64;
    }
    __syncthreads();
    bf16x8 af[4][2], bfr[4][2];
#pragma unroll
    for (int t = 0; t < 4; ++t) {
      int ra = wr * 64 + t * 16 + lr;
      int rb = wc * 64 + t * 16 + lr;
#pragma unroll
      for (int kc = 0; kc < 2; ++kc) {
        af[t][kc]  = *(const bf16x8*)&a_lds[ra * 64 + (((4 * kc + lg) ^ (ra & 7)) * 8)];
        bfr[t][kc] = *(const bf16x8*)&b_lds[rb * 64 + (((4 * kc + lg) ^ (rb & 7)) * 8)];
      }
    }
#pragma unroll
    for (int mt = 0; mt < 4; ++mt)
#pragma unroll
      for (int nt = 0; nt < 4; ++nt)
#pragma unroll
        for (int kc = 0; kc < 2; ++kc)
          acc[mt][nt] = MFMA16(af[mt][kc], bfr[nt][kc], acc[mt][nt]);
    __syncthreads();
  }

  const int hb = (n0 + wc * 64) >> 6;                 // head block (wave-uniform)
  const bool dorope = ROPE && (hb < 40);
  const float rsc = (ROPE && hb < 32) ? 0.18033688011112042f : 1.0f;

#pragma unroll
  for (int mt = 0; mt < 4; ++mt)
#pragma unroll
    for (int r = 0; r < 4; ++r) {
      int mm = m0 + wr * 64 + mt * 16 + 4 * lg + r;   // C/D: row = 4*(l>>4)+reg
      float ov[4];
      if (dorope) {
        int l = mm & 2047;
        const float* cp = cosb + l * 64 + lr;
        const float* sp = sinb + l * 64 + lr;
        float a0 = acc[mt][0][r], a1 = acc[mt][1][r];
        float a2 = acc[mt][2][r], a3 = acc[mt][3][r];
        ov[0] = (a0 * cp[0]  - a2 * sp[0])  * rsc;
        ov[1] = (a1 * cp[16] - a3 * sp[16]) * rsc;
        ov[2] = (a2 * cp[32] + a0 * sp[32]) * rsc;
        ov[3] = (a3 * cp[48] + a1 * sp[48]) * rsc;
      } else {
#pragma unroll
        for (int nt = 0; nt < 4; ++nt) ov[nt] = acc[mt][nt][r];
      }
#pragma unroll
      for (int nt = 0; nt < 4; ++nt) {
        int nn = n0 + wc * 64 + nt * 16 + lr;         // col = l&15
        C[(size_t)mm * N + nn] = (OutT)ov[nt];
      }
    }
}

// ---------------- causal GQA flash attention (swapped QK^T, 32x32) ----------
// Split-KV for u>=7 q-tiles (two half-range blocks + combine); longest-first.
__global__ __launch_bounds__(256, 4) void attn_kernel(const bf16* __restrict__ q,
                                                      const bf16* __restrict__ k,
                                                      const bf16* __restrict__ vtg,
                                                      bf16* __restrict__ o,
                                                      bf16* __restrict__ opart,
                                                      float* __restrict__ mpart,
                                                      float* __restrict__ lpart,
                                                      int split_n, int umax) {
  constexpr int L = 2048;
  constexpr int QS = 3072;
  constexpr int OS = 2048;
  const int id = blockIdx.x;
  int bh, u, ts, te, pidx;
  bool split;
  if (id < split_n) {
    bh = id & 63;
    int t = id >> 6;
    u = 15 - (t >> 1);
    int s = t & 1;
    ts = s * (u + 1);
    te = ts + (u + 1);
    pidx = (bh * 9 + (u - 7)) * 2 + s;
    split = true;
  } else {
    int e = id - split_n;
    bh = e & 63;
    u = umax - (e >> 6);
    ts = 0;
    te = 2 * u + 2;
    pidx = 0;
    split = false;
  }
  const int q0 = u * 128;
  const int b = bh >> 5, h = bh & 31, g = h >> 2;
  const int tid = threadIdx.x;
  const int w = tid >> 6, lane = tid & 63;
  const int lc = lane & 31;
  const int H  = lane >> 5;
  const int off4 = 4 * H;
  const int qw = q0 + w * 32;
  const int qg = qw + lc;

  __shared__ bf16 k_lds[2][64 * 64];
  __shared__ bf16 vt_lds[2][64 * 64];

  bf16x8 qf[4];
  {
    const bf16* qrow = q + (size_t)(b * L + qg) * QS + h * 64 + 8 * H;
#pragma unroll
    for (int s = 0; s < 4; ++s) qf[s] = *(const bf16x8*)(qrow + 16 * s);
  }

  f32x16 acc0, acc1;
#pragma unroll
  for (int r = 0; r < 16; ++r) { acc0[r] = 0.f; acc1[r] = 0.f; }
  float m_run = -1e30f, l_run = 0.f;

  const bf16* vbase = vtg + (size_t)(b * 8 + g) * 64 * L;

  const int kvr = tid >> 3, c8 = tid & 7;
  const bf16* kp0 = k + (size_t)(b * L + ts * 64 + kvr) * QS + g * 64 + ((c8 ^ (kvr & 7)) * 8);
  const bf16* kp1 = kp0 + (size_t)32 * QS;
  const bf16* vp0 = vbase + (size_t)kvr * L + ts * 64 + c8 * 8;
  const bf16* vp1 = vp0 + (size_t)32 * L;

  auto stageK = [&](int buf) {
    GLDS16(kp0, &k_lds[buf][w * 512]);
    GLDS16(kp1, &k_lds[buf][w * 512 + 2048]);
    kp0 += (size_t)64 * QS; kp1 += (size_t)64 * QS;
  };
  auto stageV = [&](int buf) {
    GLDS16(vp0, &vt_lds[buf][w * 512]);
    GLDS16(vp1, &vt_lds[buf][w * 512 + 2048]);
    vp0 += 64; vp1 += 64;
  };

  stageK(0);
  stageV(0);
  __syncthreads();

  for (int it = ts; it < te; ++it) {
    const int cur = (it - ts) & 1;
    const int kv0 = it * 64;
    const bool notlast = (it + 1 < te);
    if (notlast) {
      stageK(cur ^ 1);
      stageV(cur ^ 1);
    }

    if (kv0 <= qw + 31) {
      f32x16 p0, p1;
#pragma unroll
      for (int r = 0; r < 16; ++r) { p0[r] = 0.f; p1[r] = 0.f; }
      __builtin_amdgcn_s_setprio(1);
#pragma unroll
      for (int s = 0; s < 4; ++s) {
        int ch = ((2 * s + H) ^ (lc & 7)) * 8;
        bf16x8 kf0 = *(const bf16x8*)&k_lds[cur][lc * 64 + ch];
        bf16x8 kf1 = *(const bf16x8*)&k_lds[cur][(32 + lc) * 64 + ch];
        p0 = MFMA32(kf0, qf[s], p0);
        p1 = MFMA32(kf1, qf[s], p1);
      }
      __builtin_amdgcn_s_setprio(0);

      if (kv0 + 63 > qw) {
#pragma unroll
        for (int r = 0; r < 16; ++r) {
          int kvl = kv0 + (r & 3) + 8 * (r >> 2) + off4;
          if (kvl > qg)      p0[r] = -1e30f;
          if (kvl + 32 > qg) p1[r] = -1e30f;
        }
      }

      float mt = -1e30f;
#pragma unroll
      for (int r = 0; r < 16; ++r) mt = fmaxf(mt, fmaxf(p0[r], p1[r]));
      mt = fmaxf(mt, __shfl_xor(mt, 32));
      const int defer = __all(mt <= m_run + 11.0f);
      float alpha = 1.f;
      if (!defer) {
        float mn = fmaxf(m_run, mt);
        alpha = ex2(m_run - mn);
        m_run = mn;
      }
      float ls = 0.f;
#pragma unroll
      for (int r = 0; r < 16; ++r) {
        p0[r] = ex2(p0[r] - m_run);
        p1[r] = ex2(p1[r] - m_run);
        ls += p0[r] + p1[r];
      }
      ls += __shfl_xor(ls, 32);
      l_run = l_run * alpha + ls;
      if (!defer) {
#pragma unroll
        for (int r = 0; r < 16; ++r) {
          float aq = __shfl(alpha, ((r & 3) + 8 * (r >> 2)) + off4);
          acc0[r] *= aq;
          acc1[r] *= aq;
        }
      }

      unsigned A[16];
#pragma unroll
      for (int i = 0; i < 8; ++i) {
        A[i]     = pk2(p0[2 * i], p0[2 * i + 1]);
        A[8 + i] = pk2(p1[2 * i], p1[2 * i + 1]);
      }
#pragma unroll
      for (int base = 0; base < 16; base += 4) {
        PLSWAP(A[base],     A[base + 2]);
        PLSWAP(A[base + 1], A[base + 3]);
      }

      __builtin_amdgcn_s_setprio(1);
#pragma unroll
      for (int sp = 0; sp < 4; ++sp) {
        union { unsigned u[4]; bf16x8 v8; } pa;
#pragma unroll
        for (int jx = 0; jx < 4; ++jx) pa.u[jx] = A[4 * sp + jx];
        int ch = ((2 * sp + H) ^ (lc & 7)) * 8;
        bf16x8 vf0 = *(const bf16x8*)&vt_lds[cur][lc * 64 + ch];
        bf16x8 vf1 = *(const bf16x8*)&vt_lds[cur][(32 + lc) * 64 + ch];
        acc0 = MFMA32(pa.v8, vf0, acc0);
        acc1 = MFMA32(pa.v8, vf1, acc1);
      }
      __builtin_amdgcn_s_setprio(0);
    }

    __syncthreads();
  }

  if (split) {
    bf16* op = opart + (size_t)pidx * (128 * 64);
#pragma unroll
    for (int r = 0; r < 16; ++r) {
      int qrow = w * 32 + (r & 3) + 8 * (r >> 2) + off4;
      op[qrow * 64 + lc]      = (bf16)acc0[r];
      op[qrow * 64 + 32 + lc] = (bf16)acc1[r];
    }
    if (H == 0) {
      mpart[(size_t)pidx * 128 + w * 32 + lc] = m_run;
      lpart[(size_t)pidx * 128 + w * 32 + lc] = l_run;
    }
  } else {
#pragma unroll
    for (int r = 0; r < 16; ++r) {
      int qrow = (r & 3) + 8 * (r >> 2) + off4;
      float lq = __shfl(l_run, qrow);
      float inv = 1.f / lq;
      size_t orow = (size_t)(b * L + qw + qrow) * OS + h * 64;
      o[orow + lc]      = (bf16)(acc0[r] * inv);
      o[orow + 32 + lc] = (bf16)(acc1[r] * inv);
    }
  }
}

// ---------------- combine split-KV partials ----------------
__global__ __launch_bounds__(256) void comb_kernel(const bf16* __restrict__ opart,
                                                   const float* __restrict__ mpart,
                                                   const float* __restrict__ lpart,
                                                   bf16* __restrict__ o) {
  constexpr int L = 2048, OS = 2048;
  const int blk = blockIdx.x;
  const int bh = blk / 9, uu = blk % 9, u = uu + 7;
  const int b = bh >> 5, h = bh & 31;
  const int q0 = u * 128;
  const int t = threadIdx.x;
  const int row = t >> 1, dh = (t & 1) * 32;

  const size_t s0 = (size_t)blk * 2, s1 = s0 + 1;
  float m0 = mpart[s0 * 128 + row], m1 = mpart[s1 * 128 + row];
  float l0 = lpart[s0 * 128 + row], l1 = lpart[s1 * 128 + row];
  float m = fmaxf(m0, m1);
  float w0 = ex2(m0 - m), w1 = ex2(m1 - m);
  float inv = 1.f / (l0 * w0 + l1 * w1);

  const bf16* O0 = opart + s0 * (128 * 64) + row * 64 + dh;
  const bf16* O1 = opart + s1 * (128 * 64) + row * 64 + dh;
  bf16* orow = o + (size_t)(b * L + q0 + row) * OS + h * 64 + dh;
#pragma unroll
  for (int j = 0; j < 4; ++j) {
    bf16x8 a = *(const bf16x8*)(O0 + 8 * j);
    bf16x8 c = *(const bf16x8*)(O1 + 8 * j);
    bf16x8 r;
#pragma unroll
    for (int e = 0; e < 8; ++e)
      r[e] = (bf16)(((float)a[e] * w0 + (float)c[e] * w1) * inv);
    *(bf16x8*)(orow + 8 * j) = r;
  }
}

extern "C" void kernel_launch(void* const* d_in, const int* in_sizes, int n_in,
                              void* d_out, int out_size, void* d_ws, size_t ws_size,
                              hipStream_t stream) {
  (void)in_sizes; (void)n_in; (void)out_size;
  const float* x    = (const float*)d_in[0];
  const float* cosb = (const float*)d_in[1];
  const float* sinb = (const float*)d_in[2];
  const float* Wq   = (const float*)d_in[3];
  const float* Wk   = (const float*)d_in[4];
  const float* Wv   = (const float*)d_in[5];
  const float* Wo   = (const float*)d_in[6];

  constexpr int B = 2, L = 2048, D = 2048, H = 32, G = 8;
  constexpr int M = B * L;           // 4096
  constexpr int DKV = G * 64;        // 512
  constexpr int NQKV = D + 2 * DKV;  // 3072

  char* p = (char*)d_ws;
  bf16*  xb   = (bf16*)p;  p += (size_t)M * D * 2;
  bf16*  wqkv = (bf16*)p;  p += (size_t)NQKV * D * 2;
  bf16*  wob  = (bf16*)p;  p += (size_t)D * D * 2;
  bf16*  qkv  = (bf16*)p;  p += (size_t)M * NQKV * 2;
  bf16*  vtg  = (bf16*)p;  p += (size_t)B * G * 64 * L * 2;
  bf16*  opart = (bf16*)p; p += (size_t)1152 * 128 * 64 * 2;
  float* mpart = (float*)p; p += (size_t)1152 * 128 * 4;
  float* lpart = (float*)p; p += (size_t)1152 * 128 * 4;
  bf16*  ob   = xb;  // xb dead after QKV GEMM

  const bool do_split = ws_size >= (size_t)(p - (char*)d_ws);

  cvt5_kernel<<<dim3(18432), 256, 0, stream>>>(x, Wq, Wk, Wv, Wo, xb, wqkv, wob);

  // fused QKV projection + RoPE epilogue (m97 structure, BK=64, XCD-chunked)
  gemm_bt<bf16, true><<<dim3((NQKV / 128) * (M / 128)), 256, 0, stream>>>(
      xb, wqkv, qkv, M, NQKV, D, cosb, sinb);

  // V -> swizzled V^T global (consumed by attention via global_load_lds)
  vtr_kernel<<<dim3(L / 64, B * G), 256, 0, stream>>>(qkv + D + DKV, vtg);

  if (do_split) {
    attn_kernel<<<dim3(1600), 256, 0, stream>>>(qkv, qkv + D, vtg, ob,
                                                opart, mpart, lpart, 1152, 6);
    comb_kernel<<<dim3(576), 256, 0, stream>>>(opart, mpart, lpart, ob);
  } else {
    attn_kernel<<<dim3(1024), 256, 0, stream>>>(qkv, qkv + D, vtg, ob,
                                                opart, mpart, lpart, 0, 15);
  }

  // output projection (m97 structure, BK=64, XCD-chunked)
  gemm_bt<float, false><<<dim3((D / 128) * (M / 128)), 256, 0, stream>>>(
      ob, wob, (float*)d_out, M, D, D, nullptr, nullptr);
}

// Round 17
// 213.625 us; speedup vs baseline: 1.5497x; 1.0441x over previous
//
#include <hip/hip_runtime.h>

typedef __bf16 bf16;
typedef __bf16 bf16x4 __attribute__((ext_vector_type(4)));
typedef __bf16 bf16x8 __attribute__((ext_vector_type(8)));
typedef float  f32x4  __attribute__((ext_vector_type(4)));
typedef float  f32x16 __attribute__((ext_vector_type(16)));

#define GLDS16(gsrc, ldst)                                                    \
  __builtin_amdgcn_global_load_lds(                                          \
      (const __attribute__((address_space(1))) void*)(gsrc),                 \
      (__attribute__((address_space(3))) void*)(ldst), 16, 0, 0)

#define MFMA16(a, b, c) __builtin_amdgcn_mfma_f32_16x16x32_bf16((a), (b), (c), 0, 0, 0)
#define MFMA32(a, b, c) __builtin_amdgcn_mfma_f32_32x32x16_bf16((a), (b), (c), 0, 0, 0)
#define PLSWAP(a, b) asm volatile("v_permlane32_swap_b32 %0, %1" : "+v"(a), "+v"(b))

__device__ inline unsigned pk2(float a, float b) {
  union { bf16 h[2]; unsigned u; } t;
  t.h[0] = (bf16)a; t.h[1] = (bf16)b;
  return t.u;
}
__device__ inline float ex2(float x) { return __builtin_amdgcn_exp2f(x); }

// ---------------- fused f32 -> bf16 convert for all 5 inputs ----------------
__global__ __launch_bounds__(256) void cvt5_kernel(const float* __restrict__ x,
                                                   const float* __restrict__ wq,
                                                   const float* __restrict__ wk,
                                                   const float* __restrict__ wv,
                                                   const float* __restrict__ wo,
                                                   bf16* __restrict__ xb,
                                                   bf16* __restrict__ wqkv,
                                                   bf16* __restrict__ wob) {
  int i = blockIdx.x * 256 + threadIdx.x;
  const float* src; bf16* dst; int off;
  if (i < 2097152)      { src = x;  dst = xb;             off = i; }
  else if (i < 3145728) { src = wq; dst = wqkv;           off = i - 2097152; }
  else if (i < 3407872) { src = wk; dst = wqkv + 4194304; off = i - 3145728; }
  else if (i < 3670016) { src = wv; dst = wqkv + 5242880; off = i - 3407872; }
  else                  { src = wo; dst = wob;            off = i - 3670016; }
  f32x4 f = *(const f32x4*)(src + (size_t)off * 4);
  bf16x4 o4;
#pragma unroll
  for (int j = 0; j < 4; ++j) o4[j] = (bf16)f[j];
  *(bf16x4*)(dst + (size_t)off * 4) = o4;
}

// ---------------- V -> swizzled V^T global ([b][g][64][L]) ----------------
__global__ __launch_bounds__(256) void vtr_kernel(const bf16* __restrict__ v,
                                                  bf16* __restrict__ vt) {
  constexpr int L = 2048, QS = 3072;
  const int kv0 = blockIdx.x * 64;
  const int bg = blockIdx.y;            // b*8+g
  const int tid = threadIdx.x;
  __shared__ bf16 t[64 * 64];

#pragma unroll
  for (int i = 0; i < 2; ++i) {
    int c = tid + 256 * i;
    int kv = c >> 3, e = c & 7;
    bf16x8 row = *(const bf16x8*)(v + (size_t)((bg >> 3) * L + kv0 + kv) * QS +
                                  (bg & 7) * 64 + e * 8);
#pragma unroll
    for (int j = 0; j < 8; ++j)
      t[(8 * e + j) * 64 + (kv ^ (8 * (e ^ j)))] = row[j];
  }
  __syncthreads();

  const int d = tid >> 2, c4 = tid & 3;
  bf16* orow = vt + ((size_t)bg * 64 + d) * L + kv0;
#pragma unroll
  for (int dl = 0; dl < 2; ++dl) {
    int sc = 2 * c4 + dl;
    bf16x8 ch = *(const bf16x8*)&t[d * 64 + 8 * (sc ^ (d >> 3))];
    *(bf16x8*)(orow + 8 * sc) = ch;
  }
}

// ------------- BK=32 GEMM (R15 form): best for the QKV shape ---------------
// m97-class 128x128 tile, XCD-chunked 1D grid, ROPE epilogue.
template <typename OutT, bool ROPE>
__global__ __launch_bounds__(256) void gemm_bt32(const bf16* __restrict__ A,
                                                 const bf16* __restrict__ Bm,
                                                 OutT* __restrict__ C,
                                                 int M, int N, int K,
                                                 const float* __restrict__ cosb,
                                                 const float* __restrict__ sinb) {
  __shared__ bf16 a_lds[128 * 32];
  __shared__ bf16 b_lds[128 * 32];
  const int tid = threadIdx.x;
  const int w = tid >> 6, lane = tid & 63;
  const int lr = lane & 15, lg = lane >> 4;
  const int wr = w >> 1, wc = w & 1;
  const int nbx = N >> 7;
  const int nwg = (M >> 7) * nbx;
  const int bid = blockIdx.x;
  const int sid = (bid & 7) * (nwg >> 3) + (bid >> 3);   // XCD chunk (nwg%8==0)
  const int m0 = (sid / nbx) << 7, n0 = (sid % nbx) << 7;

  f32x4 acc[4][4];
#pragma unroll
  for (int i = 0; i < 4; ++i)
#pragma unroll
    for (int j = 0; j < 4; ++j) acc[i][j] = f32x4{0.f, 0.f, 0.f, 0.f};

  const int srow = tid >> 2, skc = (tid & 3) * 8;
  const bf16* ap0 = A  + (size_t)(m0 + srow) * K + skc;
  const bf16* ap1 = A  + (size_t)(m0 + srow + 64) * K + skc;
  const bf16* bp0 = Bm + (size_t)(n0 + srow) * K + skc;
  const bf16* bp1 = Bm + (size_t)(n0 + srow + 64) * K + skc;
  bf16* const lA0 = &a_lds[w * 512];
  bf16* const lA1 = &a_lds[w * 512 + 2048];
  bf16* const lB0 = &b_lds[w * 512];
  bf16* const lB1 = &b_lds[w * 512 + 2048];

  for (int kt = 0; kt < K; kt += 32) {
    GLDS16(ap0, lA0);
    GLDS16(ap1, lA1);
    GLDS16(bp0, lB0);
    GLDS16(bp1, lB1);
    ap0 += 32; ap1 += 32; bp0 += 32; bp1 += 32;
    __syncthreads();
    bf16x8 af[4], bfr[4];
#pragma unroll
    for (int t = 0; t < 4; ++t) {
      af[t]  = *(const bf16x8*)&a_lds[(wr * 64 + t * 16 + lr) * 32 + lg * 8];
      bfr[t] = *(const bf16x8*)&b_lds[(wc * 64 + t * 16 + lr) * 32 + lg * 8];
    }
#pragma unroll
    for (int mt = 0; mt < 4; ++mt)
#pragma unroll
      for (int nt = 0; nt < 4; ++nt)
        acc[mt][nt] = MFMA16(af[mt], bfr[nt], acc[mt][nt]);
    __syncthreads();
  }

  const int hb = (n0 + wc * 64) >> 6;
  const bool dorope = ROPE && (hb < 40);
  const float rsc = (ROPE && hb < 32) ? 0.18033688011112042f : 1.0f;

#pragma unroll
  for (int mt = 0; mt < 4; ++mt)
#pragma unroll
    for (int r = 0; r < 4; ++r) {
      int mm = m0 + wr * 64 + mt * 16 + 4 * lg + r;
      float ov[4];
      if (dorope) {
        int l = mm & 2047;
        const float* cp = cosb + l * 64 + lr;
        const float* sp = sinb + l * 64 + lr;
        float a0 = acc[mt][0][r], a1 = acc[mt][1][r];
        float a2 = acc[mt][2][r], a3 = acc[mt][3][r];
        ov[0] = (a0 * cp[0]  - a2 * sp[0])  * rsc;
        ov[1] = (a1 * cp[16] - a3 * sp[16]) * rsc;
        ov[2] = (a2 * cp[32] + a0 * sp[32]) * rsc;
        ov[3] = (a3 * cp[48] + a1 * sp[48]) * rsc;
      } else {
#pragma unroll
        for (int nt = 0; nt < 4; ++nt) ov[nt] = acc[mt][nt][r];
      }
#pragma unroll
      for (int nt = 0; nt < 4; ++nt) {
        int nn = n0 + wc * 64 + nt * 16 + lr;
        C[(size_t)mm * N + nn] = (OutT)ov[nt];
      }
    }
}

// ------------- BK=64 GEMM (R16 form): best for the O-proj shape ------------
// Half the barriers per K; chunk-XOR swizzle (conflicts measured 0).
template <typename OutT>
__global__ __launch_bounds__(256) void gemm_bt64(const bf16* __restrict__ A,
                                                 const bf16* __restrict__ Bm,
                                                 OutT* __restrict__ C,
                                                 int M, int N, int K) {
  __shared__ bf16 a_lds[128 * 64];
  __shared__ bf16 b_lds[128 * 64];
  const int tid = threadIdx.x;
  const int w = tid >> 6, lane = tid & 63;
  const int lr = lane & 15, lg = lane >> 4;
  const int wr = w >> 1, wc = w & 1;
  const int nbx = N >> 7;
  const int nwg = (M >> 7) * nbx;
  const int bid = blockIdx.x;
  const int sid = (bid & 7) * (nwg >> 3) + (bid >> 3);
  const int m0 = (sid / nbx) << 7, n0 = (sid % nbx) << 7;

  f32x4 acc[4][4];
#pragma unroll
  for (int i = 0; i < 4; ++i)
#pragma unroll
    for (int j = 0; j < 4; ++j) acc[i][j] = f32x4{0.f, 0.f, 0.f, 0.f};

  const bf16* ap[4];
  const bf16* bp[4];
#pragma unroll
  for (int i = 0; i < 4; ++i) {
    int ci = tid + 256 * i;
    int row = ci >> 3, c = ci & 7;
    int cs = c ^ (row & 7);
    ap[i] = A  + (size_t)(m0 + row) * K + cs * 8;
    bp[i] = Bm + (size_t)(n0 + row) * K + cs * 8;
  }

  for (int kt = 0; kt < K; kt += 64) {
#pragma unroll
    for (int i = 0; i < 4; ++i) {
      GLDS16(ap[i], &a_lds[w * 512 + i * 2048]);
      GLDS16(bp[i], &b_lds[w * 512 + i * 2048]);
      ap[i] += 64; bp[i] += 64;
    }
    __syncthreads();
    bf16x8 af[4][2], bfr[4][2];
#pragma unroll
    for (int t = 0; t < 4; ++t) {
      int ra = wr * 64 + t * 16 + lr;
      int rb = wc * 64 + t * 16 + lr;
#pragma unroll
      for (int kc = 0; kc < 2; ++kc) {
        af[t][kc]  = *(const bf16x8*)&a_lds[ra * 64 + (((4 * kc + lg) ^ (ra & 7)) * 8)];
        bfr[t][kc] = *(const bf16x8*)&b_lds[rb * 64 + (((4 * kc + lg) ^ (rb & 7)) * 8)];
      }
    }
#pragma unroll
    for (int mt = 0; mt < 4; ++mt)
#pragma unroll
      for (int nt = 0; nt < 4; ++nt)
#pragma unroll
        for (int kc = 0; kc < 2; ++kc)
          acc[mt][nt] = MFMA16(af[mt][kc], bfr[nt][kc], acc[mt][nt]);
    __syncthreads();
  }

#pragma unroll
  for (int mt = 0; mt < 4; ++mt)
#pragma unroll
    for (int r = 0; r < 4; ++r) {
      int mm = m0 + wr * 64 + mt * 16 + 4 * lg + r;
#pragma unroll
      for (int nt = 0; nt < 4; ++nt) {
        int nn = n0 + wc * 64 + nt * 16 + lr;
        C[(size_t)mm * N + nn] = (OutT)acc[mt][nt][r];
      }
    }
}

// ---------------- causal GQA flash attention (swapped QK^T, 32x32) ----------
// Split-KV for u>=7 q-tiles (two half-range blocks + combine); longest-first.
__global__ __launch_bounds__(256, 4) void attn_kernel(const bf16* __restrict__ q,
                                                      const bf16* __restrict__ k,
                                                      const bf16* __restrict__ vtg,
                                                      bf16* __restrict__ o,
                                                      bf16* __restrict__ opart,
                                                      float* __restrict__ mpart,
                                                      float* __restrict__ lpart,
                                                      int split_n, int umax) {
  constexpr int L = 2048;
  constexpr int QS = 3072;
  constexpr int OS = 2048;
  const int id = blockIdx.x;
  int bh, u, ts, te, pidx;
  bool split;
  if (id < split_n) {
    bh = id & 63;
    int t = id >> 6;
    u = 15 - (t >> 1);
    int s = t & 1;
    ts = s * (u + 1);
    te = ts + (u + 1);
    pidx = (bh * 9 + (u - 7)) * 2 + s;
    split = true;
  } else {
    int e = id - split_n;
    bh = e & 63;
    u = umax - (e >> 6);
    ts = 0;
    te = 2 * u + 2;
    pidx = 0;
    split = false;
  }
  const int q0 = u * 128;
  const int b = bh >> 5, h = bh & 31, g = h >> 2;
  const int tid = threadIdx.x;
  const int w = tid >> 6, lane = tid & 63;
  const int lc = lane & 31;
  const int H  = lane >> 5;
  const int off4 = 4 * H;
  const int qw = q0 + w * 32;
  const int qg = qw + lc;

  __shared__ bf16 k_lds[2][64 * 64];
  __shared__ bf16 vt_lds[2][64 * 64];

  bf16x8 qf[4];
  {
    const bf16* qrow = q + (size_t)(b * L + qg) * QS + h * 64 + 8 * H;
#pragma unroll
    for (int s = 0; s < 4; ++s) qf[s] = *(const bf16x8*)(qrow + 16 * s);
  }

  f32x16 acc0, acc1;
#pragma unroll
  for (int r = 0; r < 16; ++r) { acc0[r] = 0.f; acc1[r] = 0.f; }
  float m_run = -1e30f, l_run = 0.f;

  const bf16* vbase = vtg + (size_t)(b * 8 + g) * 64 * L;

  const int kvr = tid >> 3, c8 = tid & 7;
  const bf16* kp0 = k + (size_t)(b * L + ts * 64 + kvr) * QS + g * 64 + ((c8 ^ (kvr & 7)) * 8);
  const bf16* kp1 = kp0 + (size_t)32 * QS;
  const bf16* vp0 = vbase + (size_t)kvr * L + ts * 64 + c8 * 8;
  const bf16* vp1 = vp0 + (size_t)32 * L;

  auto stageK = [&](int buf) {
    GLDS16(kp0, &k_lds[buf][w * 512]);
    GLDS16(kp1, &k_lds[buf][w * 512 + 2048]);
    kp0 += (size_t)64 * QS; kp1 += (size_t)64 * QS;
  };
  auto stageV = [&](int buf) {
    GLDS16(vp0, &vt_lds[buf][w * 512]);
    GLDS16(vp1, &vt_lds[buf][w * 512 + 2048]);
    vp0 += 64; vp1 += 64;
  };

  stageK(0);
  stageV(0);
  __syncthreads();

  for (int it = ts; it < te; ++it) {
    const int cur = (it - ts) & 1;
    const int kv0 = it * 64;
    const bool notlast = (it + 1 < te);
    if (notlast) {
      stageK(cur ^ 1);
      stageV(cur ^ 1);
    }

    if (kv0 <= qw + 31) {
      f32x16 p0, p1;
#pragma unroll
      for (int r = 0; r < 16; ++r) { p0[r] = 0.f; p1[r] = 0.f; }
      __builtin_amdgcn_s_setprio(1);
#pragma unroll
      for (int s = 0; s < 4; ++s) {
        int ch = ((2 * s + H) ^ (lc & 7)) * 8;
        bf16x8 kf0 = *(const bf16x8*)&k_lds[cur][lc * 64 + ch];
        bf16x8 kf1 = *(const bf16x8*)&k_lds[cur][(32 + lc) * 64 + ch];
        p0 = MFMA32(kf0, qf[s], p0);
        p1 = MFMA32(kf1, qf[s], p1);
      }
      __builtin_amdgcn_s_setprio(0);

      if (kv0 + 63 > qw) {
#pragma unroll
        for (int r = 0; r < 16; ++r) {
          int kvl = kv0 + (r & 3) + 8 * (r >> 2) + off4;
          if (kvl > qg)      p0[r] = -1e30f;
          if (kvl + 32 > qg) p1[r] = -1e30f;
        }
      }

      float mt = -1e30f;
#pragma unroll
      for (int r = 0; r < 16; ++r) mt = fmaxf(mt, fmaxf(p0[r], p1[r]));
      mt = fmaxf(mt, __shfl_xor(mt, 32));
      const int defer = __all(mt <= m_run + 11.0f);
      float alpha = 1.f;
      if (!defer) {
        float mn = fmaxf(m_run, mt);
        alpha = ex2(m_run - mn);
        m_run = mn;
      }
      float ls = 0.f;
#pragma unroll
      for (int r = 0; r < 16; ++r) {
        p0[r] = ex2(p0[r] - m_run);
        p1[r] = ex2(p1[r] - m_run);
        ls += p0[r] + p1[r];
      }
      ls += __shfl_xor(ls, 32);
      l_run = l_run * alpha + ls;
      if (!defer) {
#pragma unroll
        for (int r = 0; r < 16; ++r) {
          float aq = __shfl(alpha, ((r & 3) + 8 * (r >> 2)) + off4);
          acc0[r] *= aq;
          acc1[r] *= aq;
        }
      }

      unsigned A[16];
#pragma unroll
      for (int i = 0; i < 8; ++i) {
        A[i]     = pk2(p0[2 * i], p0[2 * i + 1]);
        A[8 + i] = pk2(p1[2 * i], p1[2 * i + 1]);
      }
#pragma unroll
      for (int base = 0; base < 16; base += 4) {
        PLSWAP(A[base],     A[base + 2]);
        PLSWAP(A[base + 1], A[base + 3]);
      }

      __builtin_amdgcn_s_setprio(1);
#pragma unroll
      for (int sp = 0; sp < 4; ++sp) {
        union { unsigned u[4]; bf16x8 v8; } pa;
#pragma unroll
        for (int jx = 0; jx < 4; ++jx) pa.u[jx] = A[4 * sp + jx];
        int ch = ((2 * sp + H) ^ (lc & 7)) * 8;
        bf16x8 vf0 = *(const bf16x8*)&vt_lds[cur][lc * 64 + ch];
        bf16x8 vf1 = *(const bf16x8*)&vt_lds[cur][(32 + lc) * 64 + ch];
        acc0 = MFMA32(pa.v8, vf0, acc0);
        acc1 = MFMA32(pa.v8, vf1, acc1);
      }
      __builtin_amdgcn_s_setprio(0);
    }

    __syncthreads();
  }

  if (split) {
    bf16* op = opart + (size_t)pidx * (128 * 64);
#pragma unroll
    for (int r = 0; r < 16; ++r) {
      int qrow = w * 32 + (r & 3) + 8 * (r >> 2) + off4;
      op[qrow * 64 + lc]      = (bf16)acc0[r];
      op[qrow * 64 + 32 + lc] = (bf16)acc1[r];
    }
    if (H == 0) {
      mpart[(size_t)pidx * 128 + w * 32 + lc] = m_run;
      lpart[(size_t)pidx * 128 + w * 32 + lc] = l_run;
    }
  } else {
#pragma unroll
    for (int r = 0; r < 16; ++r) {
      int qrow = (r & 3) + 8 * (r >> 2) + off4;
      float lq = __shfl(l_run, qrow);
      float inv = 1.f / lq;
      size_t orow = (size_t)(b * L + qw + qrow) * OS + h * 64;
      o[orow + lc]      = (bf16)(acc0[r] * inv);
      o[orow + 32 + lc] = (bf16)(acc1[r] * inv);
    }
  }
}

// ---------------- combine split-KV partials ----------------
__global__ __launch_bounds__(256) void comb_kernel(const bf16* __restrict__ opart,
                                                   const float* __restrict__ mpart,
                                                   const float* __restrict__ lpart,
                                                   bf16* __restrict__ o) {
  constexpr int L = 2048, OS = 2048;
  const int blk = blockIdx.x;
  const int bh = blk / 9, uu = blk % 9, u = uu + 7;
  const int b = bh >> 5, h = bh & 31;
  const int q0 = u * 128;
  const int t = threadIdx.x;
  const int row = t >> 1, dh = (t & 1) * 32;

  const size_t s0 = (size_t)blk * 2, s1 = s0 + 1;
  float m0 = mpart[s0 * 128 + row], m1 = mpart[s1 * 128 + row];
  float l0 = lpart[s0 * 128 + row], l1 = lpart[s1 * 128 + row];
  float m = fmaxf(m0, m1);
  float w0 = ex2(m0 - m), w1 = ex2(m1 - m);
  float inv = 1.f / (l0 * w0 + l1 * w1);

  const bf16* O0 = opart + s0 * (128 * 64) + row * 64 + dh;
  const bf16* O1 = opart + s1 * (128 * 64) + row * 64 + dh;
  bf16* orow = o + (size_t)(b * L + q0 + row) * OS + h * 64 + dh;
#pragma unroll
  for (int j = 0; j < 4; ++j) {
    bf16x8 a = *(const bf16x8*)(O0 + 8 * j);
    bf16x8 c = *(const bf16x8*)(O1 + 8 * j);
    bf16x8 r;
#pragma unroll
    for (int e = 0; e < 8; ++e)
      r[e] = (bf16)(((float)a[e] * w0 + (float)c[e] * w1) * inv);
    *(bf16x8*)(orow + 8 * j) = r;
  }
}

extern "C" void kernel_launch(void* const* d_in, const int* in_sizes, int n_in,
                              void* d_out, int out_size, void* d_ws, size_t ws_size,
                              hipStream_t stream) {
  (void)in_sizes; (void)n_in; (void)out_size;
  const float* x    = (const float*)d_in[0];
  const float* cosb = (const float*)d_in[1];
  const float* sinb = (const float*)d_in[2];
  const float* Wq   = (const float*)d_in[3];
  const float* Wk   = (const float*)d_in[4];
  const float* Wv   = (const float*)d_in[5];
  const float* Wo   = (const float*)d_in[6];

  constexpr int B = 2, L = 2048, D = 2048, H = 32, G = 8;
  constexpr int M = B * L;           // 4096
  constexpr int DKV = G * 64;        // 512
  constexpr int NQKV = D + 2 * DKV;  // 3072

  char* p = (char*)d_ws;
  bf16*  xb   = (bf16*)p;  p += (size_t)M * D * 2;
  bf16*  wqkv = (bf16*)p;  p += (size_t)NQKV * D * 2;
  bf16*  wob  = (bf16*)p;  p += (size_t)D * D * 2;
  bf16*  qkv  = (bf16*)p;  p += (size_t)M * NQKV * 2;
  bf16*  vtg  = (bf16*)p;  p += (size_t)B * G * 64 * L * 2;
  bf16*  opart = (bf16*)p; p += (size_t)1152 * 128 * 64 * 2;
  float* mpart = (float*)p; p += (size_t)1152 * 128 * 4;
  float* lpart = (float*)p; p += (size_t)1152 * 128 * 4;
  bf16*  ob   = xb;  // xb dead after QKV GEMM

  const bool do_split = ws_size >= (size_t)(p - (char*)d_ws);

  cvt5_kernel<<<dim3(18432), 256, 0, stream>>>(x, Wq, Wk, Wv, Wo, xb, wqkv, wob);

  // fused QKV projection + RoPE epilogue (BK=32 variant — best for this shape)
  gemm_bt32<bf16, true><<<dim3((NQKV / 128) * (M / 128)), 256, 0, stream>>>(
      xb, wqkv, qkv, M, NQKV, D, cosb, sinb);

  // V -> swizzled V^T global (consumed by attention via global_load_lds)
  vtr_kernel<<<dim3(L / 64, B * G), 256, 0, stream>>>(qkv + D + DKV, vtg);

  if (do_split) {
    attn_kernel<<<dim3(1600), 256, 0, stream>>>(qkv, qkv + D, vtg, ob,
                                                opart, mpart, lpart, 1152, 6);
    comb_kernel<<<dim3(576), 256, 0, stream>>>(opart, mpart, lpart, ob);
  } else {
    attn_kernel<<<dim3(1024), 256, 0, stream>>>(qkv, qkv + D, vtg, ob,
                                                opart, mpart, lpart, 0, 15);
  }

  // output projection (BK=64 variant — best for this shape)
  gemm_bt64<float><<<dim3((D / 128) * (M / 128)), 256, 0, stream>>>(
      ob, wob, (float*)d_out, M, D, D);
}